// Round 14
// baseline (654.138 us; speedup 1.0000x reference)
//
#include <hip/hip_runtime.h>
#include <cstdint>
#include <cstddef>

#define NN 50000
#define EE 800000
#define EPQ (EE + NN)
#define NEG_SLOPE 0.2f
#define BN_EPS 1e-5f
#define SCB 256
#define NBLK ((NN + SCB - 1) / SCB)

typedef _Float16 f16x8 __attribute__((ext_vector_type(8)));
typedef _Float16 f16x4 __attribute__((ext_vector_type(4)));
typedef _Float16 f16x2 __attribute__((ext_vector_type(2)));
typedef float f32x4 __attribute__((ext_vector_type(4)));
typedef float f32x2 __attribute__((ext_vector_type(2)));
typedef unsigned int u32;
typedef unsigned char u8;
typedef unsigned short u16;

static __device__ __forceinline__ float lrelu(float x) { return x > 0.f ? x : x * NEG_SLOPE; }
static __device__ __forceinline__ int rfl(int v) { return __builtin_amdgcn_readfirstlane(v); }

static __device__ __forceinline__ u8 f32_to_fp8(float v) {
    return (u8)(__builtin_amdgcn_cvt_pk_fp8_f32(v, v, 0, false) & 0xff);
}
static __device__ __forceinline__ void fp8x4_to_f32(u32 v, float* o) {
    f32x2 lo = __builtin_amdgcn_cvt_pk_f32_fp8(v, false);
    f32x2 hi = __builtin_amdgcn_cvt_pk_f32_fp8(v, true);
    o[0] = lo[0]; o[1] = lo[1]; o[2] = hi[0]; o[3] = hi[1];
}

static __device__ __forceinline__ void gld_lds16(const void* g, void* l) {
    __builtin_amdgcn_global_load_lds((const __attribute__((address_space(1))) u32*)g,
                                     (__attribute__((address_space(3))) u32*)l, 16, 0, 0);
}

// ---------------- CSR build ----------------
__global__ void hist_kernel(const int* __restrict__ dst, int* __restrict__ count) {
    int e = blockIdx.x * blockDim.x + threadIdx.x;
    if (e < EE) atomicAdd(&count[dst[e]], 1);
}

__global__ __launch_bounds__(SCB) void scan1(const int* __restrict__ count,
                                             int* __restrict__ excl, int* __restrict__ bsum) {
    __shared__ int tmp[SCB];
    int b = blockIdx.x, t = threadIdx.x;
    int i = b * SCB + t;
    int v = (i < NN) ? count[i] + 1 : 0;  // +1 self loop
    tmp[t] = v;
    __syncthreads();
    for (int off = 1; off < SCB; off <<= 1) {
        int u = (t >= off) ? tmp[t - off] : 0;
        __syncthreads();
        tmp[t] += u;
        __syncthreads();
    }
    if (i < NN) excl[i] = tmp[t] - v;
    if (t == SCB - 1) bsum[b] = tmp[t];
}

__global__ __launch_bounds__(256) void scan23(const int* __restrict__ excl,
                                              const int* __restrict__ bsum,
                                              int* __restrict__ rowptr, int* __restrict__ cursor) {
    __shared__ int pre[256];
    int t = threadIdx.x;
    int v = (t < NBLK) ? bsum[t] : 0;
    pre[t] = v;
    __syncthreads();
    for (int off = 1; off < 256; off <<= 1) {
        int u = (t >= off) ? pre[t - off] : 0;
        __syncthreads();
        pre[t] += u;
        __syncthreads();
    }
    int i = blockIdx.x * blockDim.x + t;
    if (i < NN) {
        int blk = i / SCB;
        int r = excl[i] + pre[blk] - ((blk < NBLK) ? bsum[blk] : 0);
        rowptr[i] = r;
        cursor[i] = r;
    }
    if (i == NN) rowptr[NN] = EPQ;
}

__global__ void scatter_kernel(const int* __restrict__ src, const int* __restrict__ dst,
                               int* __restrict__ cursor, int* __restrict__ csrs) {
    int e = blockIdx.x * blockDim.x + threadIdx.x;
    if (e < EE) {
        int d = dst[e];
        int slot = atomicAdd(&cursor[d], 1);
        csrs[slot] = src[e];
    } else if (e < EPQ) {
        int i = e - EE;
        int slot = atomicAdd(&cursor[i], 1);
        csrs[slot] = i;
    }
}

// ---------------- unified weight transpose+cast ----------------
__global__ __launch_bounds__(256) void tcast_all(const float* __restrict__ W0,
                                                 const float* __restrict__ W1,
                                                 const float* __restrict__ W2,
                                                 _Float16* __restrict__ W0t,
                                                 _Float16* __restrict__ W1t,
                                                 _Float16* __restrict__ W2t) {
    __shared__ float tile[32][33];
    int b = blockIdx.x;
    const float* W; _Float16* Wt; int K, Nc, bx, by;
    if (b < 64)       { W = W0; Wt = W0t; K = 128; Nc = 512; int q = b;       bx = q % 16, by = q / 16; }
    else if (b < 320) { W = W1; Wt = W1t; K = 512; Nc = 512; int q = b - 64;  bx = q % 16, by = q / 16; }
    else              { W = W2; Wt = W2t; K = 512; Nc = 240; int q = b - 320; bx = q % 8,  by = q / 8; }
    bx *= 32; by *= 32;
    int tx = threadIdx.x & 31, ty = threadIdx.x >> 5;
#pragma unroll
    for (int r = 0; r < 32; r += 8) {
        int k = by + ty + r, n = bx + tx;
        tile[ty + r][tx] = (k < K && n < Nc) ? W[(size_t)k * Nc + n] : 0.f;
    }
    __syncthreads();
#pragma unroll
    for (int r = 0; r < 32; r += 8) {
        int n = bx + ty + r, k = by + tx;
        if (n < Nc && k < K) Wt[(size_t)n * K + k] = (_Float16)tile[tx][ty + r];
    }
}

// ---------------- unified prep ----------------
__global__ __launch_bounds__(1024) void prep_all(const float* g0, const float* bt0,
                                                 const float* m0, const float* v0, const float* b0,
                                                 const float* g1, const float* bt1,
                                                 const float* m1, const float* v1, const float* b1,
                                                 const _Float16* __restrict__ W0t,
                                                 const _Float16* __restrict__ W1t,
                                                 const _Float16* __restrict__ W2t,
                                                 const float* __restrict__ as0,
                                                 const float* __restrict__ ad0,
                                                 const float* __restrict__ as1,
                                                 const float* __restrict__ ad1,
                                                 const float* __restrict__ as2,
                                                 const float* __restrict__ ad2,
                                                 float* sc01, float* sh01, float* va0, float* va1,
                                                 float* va2) {
    int bid = blockIdx.x, t = threadIdx.x;
    if (bid == 0) {
        const float *g, *bt, *m, *v, *b;
        int c;
        if (t < 512) { g = g0; bt = bt0; m = m0; v = v0; b = b0; c = t; }
        else         { g = g1; bt = bt1; m = m1; v = v1; b = b1; c = t - 512; }
        float s = g[c] * rsqrtf(v[c] + BN_EPS);
        sc01[t] = s;
        sh01[t] = (b[c] - m[c]) * s + bt[c];
        return;
    }
    int vb = bid - 1;
    if (vb < 8) {
        if (t >= 128) return;
        int j = vb, h = j & 3;
        const float* a = (j < 4 ? as0 : ad0) + h * 128;
        float s = 0.f;
        for (int c = 0; c < 128; c++) s += (float)W0t[(size_t)(h * 128 + c) * 128 + t] * a[c];
        va0[j * 128 + t] = s;
    } else if (vb < 16) {
        if (t >= 512) return;
        int j = vb - 8, h = j & 3;
        const float* a = (j < 4 ? as1 : ad1) + h * 128;
        float s = 0.f;
        for (int c = 0; c < 128; c++) s += (float)W1t[(size_t)(h * 128 + c) * 512 + t] * a[c];
        va1[j * 512 + t] = s;
    } else {
        if (t >= 512) return;
        int j = vb - 16, h = j % 6;
        const float* a = (j < 6 ? as2 : ad2) + h * 40;
        float s = 0.f;
        for (int c = 0; c < 40; c++) s += (float)W2t[(size_t)(h * 40 + c) * 512 + t] * a[c];
        va2[j * 512 + t] = s;
    }
}

// ---------------- fused: cast x -> fp8 table + L0 alpha dots ----------------
__global__ __launch_bounds__(256) void castx_alpha0(const float* __restrict__ x,
                                                    const float* __restrict__ va0,
                                                    u8* __restrict__ xq, float* __restrict__ asn,
                                                    float* __restrict__ adn) {
    int wid = threadIdx.x >> 6, lane = threadIdx.x & 63;
    int i = blockIdx.x * 4 + wid;
    if (i >= NN) return;
    f32x2 xv = *(const f32x2*)(x + (size_t)i * 128 + lane * 2);
    u32 q = __builtin_amdgcn_cvt_pk_fp8_f32(xv[0], xv[1], 0, false);
    *((u16*)(xq + (size_t)i * 128) + lane) = (u16)(q & 0xffff);
    float p[8];
#pragma unroll
    for (int j = 0; j < 8; j++) {
        f32x2 v = *(const f32x2*)(va0 + j * 128 + lane * 2);
        p[j] = xv[0] * v[0] + xv[1] * v[1];
    }
#pragma unroll
    for (int off = 32; off; off >>= 1)
#pragma unroll
        for (int j = 0; j < 8; j++) p[j] += __shfl_xor(p[j], off);
    if (lane == 0) {
        f32x4 o0 = {p[0], p[1], p[2], p[3]}, o1 = {p[4], p[5], p[6], p[7]};
        *(f32x4*)(asn + (size_t)i * 4) = o0;
        *(f32x4*)(adn + (size_t)i * 4) = o1;
    }
}

// ---------------- f16 MFMA GEMM; TK compile-time K; AL: fuse next-layer alpha dots --------
template <int TK, bool BD, bool EPI, int OT, bool AL>
__global__ __launch_bounds__(256) void gemm_t(const _Float16* __restrict__ A, int lda,
                                              const _Float16* __restrict__ Bt,
                                              void* __restrict__ Cv, int ldc, int M, int Nc,
                                              const float* __restrict__ sc,
                                              const float* __restrict__ sh,
                                              const float* __restrict__ va,
                                              float* __restrict__ asnO,
                                              float* __restrict__ adnO) {
    __shared__ __align__(16) _Float16 As[2][128 * 64];
    __shared__ __align__(16) _Float16 Bs[2][128 * 64];
    const int t = threadIdx.x;
    const int bm = blockIdx.x * 128;
    const int bn = blockIdx.y * 128;
    const int wid = t >> 6, lane = t & 63;
    const int wm = (wid >> 1) * 64, wn = (wid & 1) * 64;
    const int aoff = BD ? bn : 0;
    f32x4 acc[4][4] = {};
    constexpr int nsteps = TK >> 6;

    auto STAGE = [&](int buf, int k0) {
#pragma unroll
        for (int it = 0; it < 4; ++it) {
            int rbase = it * 32 + wid * 8;
            int row = rbase + (lane >> 3);
            int c8g = (lane & 7) ^ (row & 7);
            gld_lds16(A + (size_t)(bm + row) * lda + aoff + k0 + c8g * 8,
                      (char*)As[buf] + rbase * 128);
            gld_lds16(Bt + (size_t)(bn + row) * TK + k0 + c8g * 8, (char*)Bs[buf] + rbase * 128);
        }
    };

    STAGE(0, 0);
    __syncthreads();
#pragma unroll
    for (int s = 0; s < nsteps; ++s) {
        const int cur = s & 1;
        if (s + 1 < nsteps) STAGE(cur ^ 1, (s + 1) * 64);
#pragma unroll
        for (int ks = 0; ks < 2; ++ks) {
            f16x8 af[4], bf[4];
#pragma unroll
            for (int mi = 0; mi < 4; ++mi) {
                int row = wm + mi * 16 + (lane & 15);
                int c8 = (ks * 4 + (lane >> 4)) ^ (row & 7);
                af[mi] = *(const f16x8*)((const char*)As[cur] + row * 128 + c8 * 16);
            }
#pragma unroll
            for (int ni = 0; ni < 4; ++ni) {
                int row = wn + ni * 16 + (lane & 15);
                int c8 = (ks * 4 + (lane >> 4)) ^ (row & 7);
                bf[ni] = *(const f16x8*)((const char*)Bs[cur] + row * 128 + c8 * 16);
            }
#pragma unroll
            for (int mi = 0; mi < 4; ++mi)
#pragma unroll
                for (int ni = 0; ni < 4; ++ni)
                    acc[mi][ni] = __builtin_amdgcn_mfma_f32_16x16x32_f16(af[mi], bf[ni],
                                                                         acc[mi][ni], 0, 0, 0);
        }
        __syncthreads();
    }
    float scv[4], shv[4];
    if (EPI) {
#pragma unroll
        for (int ni = 0; ni < 4; ++ni) {
            int gcol = bn + wn + ni * 16 + (lane & 15);
            scv[ni] = sc[gcol];
            shv[ni] = sh[gcol];
        }
    }
    float vaj[8][4];
    if (AL) {
#pragma unroll
        for (int j = 0; j < 8; ++j)
#pragma unroll
            for (int ni = 0; ni < 4; ++ni)
                vaj[j][ni] = va[j * 512 + bn + wn + ni * 16 + (lane & 15)];
    }
#pragma unroll
    for (int mi = 0; mi < 4; ++mi) {
#pragma unroll
        for (int r = 0; r < 4; ++r) {
            int grow = bm + wm + mi * 16 + (lane >> 4) * 4 + r;
            if (grow < M) {
                float pj[8] = {};
#pragma unroll
                for (int ni = 0; ni < 4; ++ni) {
                    int gcol = bn + wn + ni * 16 + (lane & 15);
                    if (gcol < Nc) {
                        float v = acc[mi][ni][r];
                        if (EPI) {
                            v = v * scv[ni] + shv[ni];
                            v = v > 0.f ? v : expm1f(v);
                        }
                        if constexpr (OT == 0) {
                            ((_Float16*)Cv)[(size_t)grow * ldc + gcol] = (_Float16)v;
                        } else {
                            ((u8*)Cv)[(size_t)grow * ldc + gcol] = f32_to_fp8(v);
                        }
                        if (AL) {
#pragma unroll
                            for (int j = 0; j < 8; ++j) pj[j] += v * vaj[j][ni];
                        }
                    }
                }
                if (AL) {
#pragma unroll
                    for (int off = 1; off < 16; off <<= 1)
#pragma unroll
                        for (int j = 0; j < 8; ++j) pj[j] += __shfl_xor(pj[j], off);
                    if ((lane & 15) == 0) {
#pragma unroll
                        for (int j = 0; j < 4; ++j) {
                            atomicAdd(&asnO[(size_t)grow * 4 + j], pj[j]);
                            atomicAdd(&adnO[(size_t)grow * 4 + j], pj[4 + j]);
                        }
                    }
                }
            }
        }
    }
}

// ---------------- L0: fused softmax + x-space aggregation (fp8 x, 4-edge unroll) ----------
__global__ __launch_bounds__(256) void aggx(const u8* __restrict__ xq,
                                            const float* __restrict__ asn,
                                            const float* __restrict__ adn,
                                            const int* __restrict__ rowptr,
                                            const int* __restrict__ csr,
                                            _Float16* __restrict__ xa) {
    __shared__ __align__(8) _Float16 wsl[4][64][4];
    int wid = threadIdx.x >> 6, lane = threadIdx.x & 63;
    int i = blockIdx.x * 4 + wid;
    if (i >= NN) return;
    int start = rfl(rowptr[i]), end = rfl(rowptr[i + 1]);
    int deg = end - start;
    bool fastp = deg <= 64;
    f32x4 ad = *(const f32x4*)(adn + (size_t)i * 4);
    f32x4 m4, rd4;
    if (fastp) {
        bool v = lane < deg;
        int e = start + (v ? lane : 0);
        int s = csr[e];
        f32x4 a = *(const f32x4*)(asn + (size_t)s * 4);
        f32x4 sc4, mm, wv, dn;
#pragma unroll
        for (int j = 0; j < 4; j++) { sc4[j] = v ? lrelu(a[j] + ad[j]) : -1e30f; mm[j] = sc4[j]; }
#pragma unroll
        for (int off = 32; off; off >>= 1)
#pragma unroll
            for (int j = 0; j < 4; j++) mm[j] = fmaxf(mm[j], __shfl_xor(mm[j], off));
#pragma unroll
        for (int j = 0; j < 4; j++) { wv[j] = v ? __expf(sc4[j] - mm[j]) : 0.f; dn[j] = wv[j]; }
#pragma unroll
        for (int off = 32; off; off >>= 1)
#pragma unroll
            for (int j = 0; j < 4; j++) dn[j] += __shfl_xor(dn[j], off);
        f16x4 o;
#pragma unroll
        for (int j = 0; j < 4; j++) o[j] = (_Float16)(wv[j] / (dn[j] + 1e-16f));
        *(f16x4*)&wsl[wid][lane][0] = o;
    } else {
        f32x4 mm = {-1e30f, -1e30f, -1e30f, -1e30f};
        for (int e = start + lane; e < end; e += 64) {
            int s = csr[e];
            f32x4 a = *(const f32x4*)(asn + (size_t)s * 4);
#pragma unroll
            for (int j = 0; j < 4; j++) mm[j] = fmaxf(mm[j], lrelu(a[j] + ad[j]));
        }
#pragma unroll
        for (int off = 32; off; off >>= 1)
#pragma unroll
            for (int j = 0; j < 4; j++) mm[j] = fmaxf(mm[j], __shfl_xor(mm[j], off));
        f32x4 dn = {0.f, 0.f, 0.f, 0.f};
        for (int e = start + lane; e < end; e += 64) {
            int s = csr[e];
            f32x4 a = *(const f32x4*)(asn + (size_t)s * 4);
#pragma unroll
            for (int j = 0; j < 4; j++) dn[j] += __expf(lrelu(a[j] + ad[j]) - mm[j]);
        }
#pragma unroll
        for (int off = 32; off; off >>= 1)
#pragma unroll
            for (int j = 0; j < 4; j++) dn[j] += __shfl_xor(dn[j], off);
        m4 = mm;
#pragma unroll
        for (int j = 0; j < 4; j++) rd4[j] = 1.f / (dn[j] + 1e-16f);
    }
    const char* xb = (const char*)xq + lane * 2;
    float acc[8] = {};
    int e = start;
    auto getw = [&](int ee, int ss, float* w) {
        if (fastp) {
            f16x4 wv4 = *(const f16x4*)&wsl[wid][ee - start][0];
#pragma unroll
            for (int h = 0; h < 4; h++) w[h] = (float)wv4[h];
        } else {
#pragma unroll
            for (int h = 0; h < 4; h++)
                w[h] = __expf(lrelu(asn[(size_t)ss * 4 + h] + ad[h]) - m4[h]) * rd4[h];
        }
    };
    for (; e + 4 <= end; e += 4) {
        int4 sv = *(const int4*)(csr + e);
        int s0 = rfl(sv.x), s1 = rfl(sv.y), s2 = rfl(sv.z), s3 = rfl(sv.w);
        u16 pv0 = *(const u16*)(xb + (u32)s0 * 128u);
        u16 pv1 = *(const u16*)(xb + (u32)s1 * 128u);
        u16 pv2 = *(const u16*)(xb + (u32)s2 * 128u);
        u16 pv3 = *(const u16*)(xb + (u32)s3 * 128u);
        float w0[4], w1[4], w2[4], w3[4];
        getw(e, s0, w0); getw(e + 1, s1, w1); getw(e + 2, s2, w2); getw(e + 3, s3, w3);
        f32x2 q0 = __builtin_amdgcn_cvt_pk_f32_fp8((u32)pv0, false);
        f32x2 q1 = __builtin_amdgcn_cvt_pk_f32_fp8((u32)pv1, false);
        f32x2 q2 = __builtin_amdgcn_cvt_pk_f32_fp8((u32)pv2, false);
        f32x2 q3 = __builtin_amdgcn_cvt_pk_f32_fp8((u32)pv3, false);
#pragma unroll
        for (int h = 0; h < 4; h++) {
            acc[h * 2]     += w0[h] * q0[0] + w1[h] * q1[0] + w2[h] * q2[0] + w3[h] * q3[0];
            acc[h * 2 + 1] += w0[h] * q0[1] + w1[h] * q1[1] + w2[h] * q2[1] + w3[h] * q3[1];
        }
    }
    for (; e < end; e++) {
        int s = rfl(csr[e]);
        float w[4];
        getw(e, s, w);
        u16 pv = *(const u16*)(xb + (u32)s * 128u);
        f32x2 q = __builtin_amdgcn_cvt_pk_f32_fp8((u32)pv, false);
#pragma unroll
        for (int h = 0; h < 4; h++) {
            acc[h * 2] += w[h] * q[0];
            acc[h * 2 + 1] += w[h] * q[1];
        }
    }
#pragma unroll
    for (int h = 0; h < 4; h++) {
        f16x2 o;
        o[0] = (_Float16)acc[h * 2];
        o[1] = (_Float16)acc[h * 2 + 1];
        *(f16x2*)(xa + (size_t)i * 512 + h * 128 + lane * 2) = o;
    }
}

// ---------------- L1: fused softmax + fp8 gather + BN/ELU + L2 alpha dots ----------
__global__ __launch_bounds__(256) void agg01(const u8* __restrict__ h,
                                             const float* __restrict__ asn,
                                             const float* __restrict__ adn,
                                             const int* __restrict__ rowptr,
                                             const int* __restrict__ csr,
                                             const float* __restrict__ sc,
                                             const float* __restrict__ sh,
                                             const float* __restrict__ va2,
                                             _Float16* __restrict__ out,
                                             float* __restrict__ asnC,
                                             float* __restrict__ adnC) {
    __shared__ __align__(8) _Float16 wsl[4][64][4];
    int wid = threadIdx.x >> 6, lane = threadIdx.x & 63;
    int i = blockIdx.x * 4 + wid;
    if (i >= NN) return;
    int start = rfl(rowptr[i]), end = rfl(rowptr[i + 1]);
    int deg = end - start;
    bool fastp = deg <= 64;
    f32x4 ad = *(const f32x4*)(adn + (size_t)i * 4);
    f32x4 m4, rd4;
    if (fastp) {
        bool v = lane < deg;
        int e = start + (v ? lane : 0);
        int s = csr[e];
        f32x4 a = *(const f32x4*)(asn + (size_t)s * 4);
        f32x4 sc4, mm, wv, dn;
#pragma unroll
        for (int j = 0; j < 4; j++) { sc4[j] = v ? lrelu(a[j] + ad[j]) : -1e30f; mm[j] = sc4[j]; }
#pragma unroll
        for (int off = 32; off; off >>= 1)
#pragma unroll
            for (int j = 0; j < 4; j++) mm[j] = fmaxf(mm[j], __shfl_xor(mm[j], off));
#pragma unroll
        for (int j = 0; j < 4; j++) { wv[j] = v ? __expf(sc4[j] - mm[j]) : 0.f; dn[j] = wv[j]; }
#pragma unroll
        for (int off = 32; off; off >>= 1)
#pragma unroll
            for (int j = 0; j < 4; j++) dn[j] += __shfl_xor(dn[j], off);
        f16x4 o;
#pragma unroll
        for (int j = 0; j < 4; j++) o[j] = (_Float16)(wv[j] / (dn[j] + 1e-16f));
        *(f16x4*)&wsl[wid][lane][0] = o;
    } else {
        f32x4 mm = {-1e30f, -1e30f, -1e30f, -1e30f};
        for (int e = start + lane; e < end; e += 64) {
            int s = csr[e];
            f32x4 a = *(const f32x4*)(asn + (size_t)s * 4);
#pragma unroll
            for (int j = 0; j < 4; j++) mm[j] = fmaxf(mm[j], lrelu(a[j] + ad[j]));
        }
#pragma unroll
        for (int off = 32; off; off >>= 1)
#pragma unroll
            for (int j = 0; j < 4; j++) mm[j] = fmaxf(mm[j], __shfl_xor(mm[j], off));
        f32x4 dn = {0.f, 0.f, 0.f, 0.f};
        for (int e = start + lane; e < end; e += 64) {
            int s = csr[e];
            f32x4 a = *(const f32x4*)(asn + (size_t)s * 4);
#pragma unroll
            for (int j = 0; j < 4; j++) dn[j] += __expf(lrelu(a[j] + ad[j]) - mm[j]);
        }
#pragma unroll
        for (int off = 32; off; off >>= 1)
#pragma unroll
            for (int j = 0; j < 4; j++) dn[j] += __shfl_xor(dn[j], off);
        m4 = mm;
#pragma unroll
        for (int j = 0; j < 4; j++) rd4[j] = 1.f / (dn[j] + 1e-16f);
    }
    int head = lane >> 4;
    const char* hb = (const char*)h + lane * 8;
    float acc0[8] = {}, acc1[8] = {};
    int e = start;
    for (; e + 2 <= end; e += 2) {
        int2 sv = *(const int2*)(csr + e);
        int s0 = rfl(sv.x), s1 = rfl(sv.y);
        float w0, w1;
        if (fastp) {
            w0 = (float)wsl[wid][e - start][head];
            w1 = (float)wsl[wid][e + 1 - start][head];
        } else {
            w0 = __expf(lrelu(asn[(size_t)s0 * 4 + head] + ad[head]) - m4[head]) * rd4[head];
            w1 = __expf(lrelu(asn[(size_t)s1 * 4 + head] + ad[head]) - m4[head]) * rd4[head];
        }
        uint2 p0 = *(const uint2*)(hb + (u32)s0 * 512u);
        uint2 p1 = *(const uint2*)(hb + (u32)s1 * 512u);
        float q0[8], q1[8];
        fp8x4_to_f32(p0.x, q0); fp8x4_to_f32(p0.y, q0 + 4);
        fp8x4_to_f32(p1.x, q1); fp8x4_to_f32(p1.y, q1 + 4);
#pragma unroll
        for (int j = 0; j < 8; j++) {
            acc0[j] += w0 * q0[j];
            acc1[j] += w1 * q1[j];
        }
    }
    if (e < end) {
        int s0 = rfl(csr[e]);
        float w0;
        if (fastp) w0 = (float)wsl[wid][e - start][head];
        else w0 = __expf(lrelu(asn[(size_t)s0 * 4 + head] + ad[head]) - m4[head]) * rd4[head];
        uint2 p0 = *(const uint2*)(hb + (u32)s0 * 512u);
        float q0[8];
        fp8x4_to_f32(p0.x, q0); fp8x4_to_f32(p0.y, q0 + 4);
#pragma unroll
        for (int j = 0; j < 8; j++) acc0[j] += w0 * q0[j];
    }
    int ch = lane * 8;
    f32x4 sc0 = *(const f32x4*)(sc + ch), sc1 = *(const f32x4*)(sc + ch + 4);
    f32x4 sh0 = *(const f32x4*)(sh + ch), sh1 = *(const f32x4*)(sh + ch + 4);
    f16x8 o;
    float valf[8];
#pragma unroll
    for (int j = 0; j < 8; j++) {
        float s = (j < 4) ? sc0[j] : sc1[j - 4];
        float b = (j < 4) ? sh0[j] : sh1[j - 4];
        float val = (acc0[j] + acc1[j]) * s + b;
        val = val > 0.f ? val : expm1f(val);
        valf[j] = val;
        o[j] = (_Float16)val;
    }
    *(f16x8*)(out + (size_t)i * 512 + ch) = o;
    // L2 alpha dots: full row is in this wave
    float pj[12];
#pragma unroll
    for (int j = 0; j < 12; j++) {
        const float* vr = va2 + j * 512 + ch;
        f32x4 v0 = *(const f32x4*)vr;
        f32x4 v1 = *(const f32x4*)(vr + 4);
        pj[j] = valf[0] * v0[0] + valf[1] * v0[1] + valf[2] * v0[2] + valf[3] * v0[3] +
                valf[4] * v1[0] + valf[5] * v1[1] + valf[6] * v1[2] + valf[7] * v1[3];
    }
#pragma unroll
    for (int off = 32; off; off >>= 1)
#pragma unroll
        for (int j = 0; j < 12; j++) pj[j] += __shfl_xor(pj[j], off);
    if (lane == 0) {
#pragma unroll
        for (int hh = 0; hh < 6; hh++) {
            asnC[(size_t)i * 8 + hh] = pj[hh];
            adnC[(size_t)i * 8 + hh] = pj[6 + hh];
        }
    }
}

// ---------------- L2: fused softmax (6 heads) + fp8 gather (4-edge) + log_softmax ----------
__global__ __launch_bounds__(256) void agg2f(const u8* __restrict__ h2,
                                             const float* __restrict__ asn,
                                             const float* __restrict__ adn,
                                             const int* __restrict__ rowptr,
                                             const int* __restrict__ csr,
                                             const float* __restrict__ b2,
                                             float* __restrict__ out) {
    __shared__ __align__(16) _Float16 wsl[4][64][8];
    __shared__ float sval[4][240];
    int wid = threadIdx.x >> 6, lane = threadIdx.x & 63;
    int i = blockIdx.x * 4 + wid;
    if (i < NN) {
        int start = rfl(rowptr[i]), end = rfl(rowptr[i + 1]);
        int deg = end - start;
        bool fastp = deg <= 64;
        f32x4 ad0 = *(const f32x4*)(adn + (size_t)i * 8);
        f32x4 ad1 = *(const f32x4*)(adn + (size_t)i * 8 + 4);
        float adh[6] = {ad0[0], ad0[1], ad0[2], ad0[3], ad1[0], ad1[1]};
        float m6[6], rd6[6];
        if (fastp) {
            bool v = lane < deg;
            int e = start + (v ? lane : 0);
            int s = csr[e];
            f32x4 x0 = *(const f32x4*)(asn + (size_t)s * 8);
            f32x4 x1 = *(const f32x4*)(asn + (size_t)s * 8 + 4);
            float av[6] = {x0[0], x0[1], x0[2], x0[3], x1[0], x1[1]};
            float sc6[6], mm[6], wv[6], dn[6];
#pragma unroll
            for (int j = 0; j < 6; j++) {
                sc6[j] = v ? lrelu(av[j] + adh[j]) : -1e30f;
                mm[j] = sc6[j];
            }
#pragma unroll
            for (int off = 32; off; off >>= 1)
#pragma unroll
                for (int j = 0; j < 6; j++) mm[j] = fmaxf(mm[j], __shfl_xor(mm[j], off));
#pragma unroll
            for (int j = 0; j < 6; j++) { wv[j] = v ? __expf(sc6[j] - mm[j]) : 0.f; dn[j] = wv[j]; }
#pragma unroll
            for (int off = 32; off; off >>= 1)
#pragma unroll
                for (int j = 0; j < 6; j++) dn[j] += __shfl_xor(dn[j], off);
            f16x8 o;
#pragma unroll
            for (int j = 0; j < 6; j++) o[j] = (_Float16)(wv[j] / (dn[j] + 1e-16f));
            o[6] = (_Float16)0.f;
            o[7] = (_Float16)0.f;
            *(f16x8*)&wsl[wid][lane][0] = o;
        } else {
            float mm[6], dn[6];
#pragma unroll
            for (int j = 0; j < 6; j++) { mm[j] = -1e30f; dn[j] = 0.f; }
            for (int e = start + lane; e < end; e += 64) {
                int s = csr[e];
                f32x4 x0 = *(const f32x4*)(asn + (size_t)s * 8);
                f32x4 x1 = *(const f32x4*)(asn + (size_t)s * 8 + 4);
                float av[6] = {x0[0], x0[1], x0[2], x0[3], x1[0], x1[1]};
#pragma unroll
                for (int j = 0; j < 6; j++) mm[j] = fmaxf(mm[j], lrelu(av[j] + adh[j]));
            }
#pragma unroll
            for (int off = 32; off; off >>= 1)
#pragma unroll
                for (int j = 0; j < 6; j++) mm[j] = fmaxf(mm[j], __shfl_xor(mm[j], off));
            for (int e = start + lane; e < end; e += 64) {
                int s = csr[e];
                f32x4 x0 = *(const f32x4*)(asn + (size_t)s * 8);
                f32x4 x1 = *(const f32x4*)(asn + (size_t)s * 8 + 4);
                float av[6] = {x0[0], x0[1], x0[2], x0[3], x1[0], x1[1]};
#pragma unroll
                for (int j = 0; j < 6; j++) dn[j] += __expf(lrelu(av[j] + adh[j]) - mm[j]);
            }
#pragma unroll
            for (int off = 32; off; off >>= 1)
#pragma unroll
                for (int j = 0; j < 6; j++) dn[j] += __shfl_xor(dn[j], off);
#pragma unroll
            for (int j = 0; j < 6; j++) { m6[j] = mm[j]; rd6[j] = 1.f / (dn[j] + 1e-16f); }
        }
        int head = (lane < 60) ? (lane / 10) : 0;
        const char* hb = (const char*)h2 + lane * 4;
        float a0[4] = {}, a1[4] = {};
        int e = start;
        auto getw1 = [&](int ee, int ss) -> float {
            if (fastp) return (float)wsl[wid][ee - start][head];
            return __expf(lrelu(asn[(size_t)ss * 8 + head] + adh[head]) - m6[head]) * rd6[head];
        };
        for (; e + 4 <= end; e += 4) {
            int4 sv = *(const int4*)(csr + e);
            int s0 = rfl(sv.x), s1 = rfl(sv.y), s2 = rfl(sv.z), s3 = rfl(sv.w);
            u32 p0 = *(const u32*)(hb + (u32)s0 * 256u);
            u32 p1 = *(const u32*)(hb + (u32)s1 * 256u);
            u32 p2 = *(const u32*)(hb + (u32)s2 * 256u);
            u32 p3 = *(const u32*)(hb + (u32)s3 * 256u);
            float w0 = getw1(e, s0), w1 = getw1(e + 1, s1);
            float w2 = getw1(e + 2, s2), w3 = getw1(e + 3, s3);
            float q0[4], q1[4], q2[4], q3[4];
            fp8x4_to_f32(p0, q0);
            fp8x4_to_f32(p1, q1);
            fp8x4_to_f32(p2, q2);
            fp8x4_to_f32(p3, q3);
#pragma unroll
            for (int j = 0; j < 4; j++) {
                a0[j] += w0 * q0[j] + w2 * q2[j];
                a1[j] += w1 * q1[j] + w3 * q3[j];
            }
        }
        for (; e < end; e++) {
            int s0 = rfl(csr[e]);
            float w0 = getw1(e, s0);
            u32 p0 = *(const u32*)(hb + (u32)s0 * 256u);
            float q0[4];
            fp8x4_to_f32(p0, q0);
#pragma unroll
            for (int j = 0; j < 4; j++) a0[j] += w0 * q0[j];
        }
        if (lane < 60) {
#pragma unroll
            for (int j = 0; j < 4; j++) sval[wid][lane * 4 + j] = a0[j] + a1[j];
        }
    }
    __syncthreads();
    if (i < NN) {
        float v = -INFINITY;
        if (lane < 40) {
            float s = 0.f;
#pragma unroll
            for (int hh = 0; hh < 6; hh++) s += sval[wid][hh * 40 + lane];
            v = s * (1.0f / 6.0f) + b2[lane];
        }
        float mm = v;
#pragma unroll
        for (int off = 32; off; off >>= 1) mm = fmaxf(mm, __shfl_xor(mm, off));
        float se = (lane < 40) ? __expf(v - mm) : 0.f;
#pragma unroll
        for (int off = 32; off; off >>= 1) se += __shfl_xor(se, off);
        if (lane < 40) out[(size_t)i * 40 + lane] = v - mm - logf(se);
    }
}

extern "C" void kernel_launch(void* const* d_in, const int* in_sizes, int n_in,
                              void* d_out, int out_size, void* d_ws, size_t ws_size,
                              hipStream_t stream) {
    const float* x   = (const float*)d_in[0];
    const int*   ei  = (const int*)d_in[1];
    const float* W0  = (const float*)d_in[2];
    const float* as0 = (const float*)d_in[3];
    const float* ad0 = (const float*)d_in[4];
    const float* b0  = (const float*)d_in[5];
    const float* g0  = (const float*)d_in[6];
    const float* bt0 = (const float*)d_in[7];
    const float* m0  = (const float*)d_in[8];
    const float* v0  = (const float*)d_in[9];
    const float* W1  = (const float*)d_in[10];
    const float* as1 = (const float*)d_in[11];
    const float* ad1 = (const float*)d_in[12];
    const float* b1  = (const float*)d_in[13];
    const float* g1  = (const float*)d_in[14];
    const float* bt1 = (const float*)d_in[15];
    const float* m1  = (const float*)d_in[16];
    const float* v1  = (const float*)d_in[17];
    const float* W2  = (const float*)d_in[18];
    const float* as2w = (const float*)d_in[19];
    const float* ad2w = (const float*)d_in[20];
    const float* b2  = (const float*)d_in[21];
    float* out = (float*)d_out;
    const int* srcv = ei;
    const int* dstv = ei + EE;

    char* w = (char*)d_ws;
    auto carve = [&](size_t bytes) {
        char* p = w;
        w += (bytes + 255) & ~(size_t)255;
        return p;
    };
    u32* xq        = (u32*)carve((size_t)NN * 128);
    _Float16* hA   = (_Float16*)carve((size_t)NN * 512 * 2);
    _Float16* actB = (_Float16*)carve((size_t)NN * 512 * 2);
    _Float16* W0t  = (_Float16*)carve((size_t)512 * 128 * 2);
    _Float16* W1t  = (_Float16*)carve((size_t)512 * 512 * 2);
    _Float16* W2t  = (_Float16*)carve((size_t)240 * 512 * 2);
    float* va0  = (float*)carve((size_t)8 * 128 * 4);
    float* va1  = (float*)carve((size_t)8 * 512 * 4);
    float* va2  = (float*)carve((size_t)12 * 512 * 4);
    float* sc01 = (float*)carve((size_t)1024 * 4);
    float* sh01 = (float*)carve((size_t)1024 * 4);
    float* asnA = (float*)carve((size_t)NN * 4 * 4);
    float* adnA = (float*)carve((size_t)NN * 4 * 4);
    // contiguous zero-region: asnB, adnB, count (one memset)
    float* asnB = (float*)carve((size_t)NN * 4 * 4);     // 800000 B (256-aligned)
    float* adnB = (float*)carve((size_t)NN * 4 * 4);
    int* count  = (int*)carve((size_t)(NN + 8) * 4);
    float* asnC = (float*)carve((size_t)NN * 8 * 4);
    float* adnC = (float*)carve((size_t)NN * 8 * 4);
    int* excl   = (int*)carve((size_t)(NN + 8) * 4);
    int* bsum   = (int*)carve((size_t)512 * 4);
    int* rowptr = (int*)carve((size_t)(NN + 8) * 4);
    int* cursor = (int*)carve((size_t)(NN + 8) * 4);
    int* csrs   = (int*)carve((size_t)(EPQ + 8) * 4);
    _Float16* xa = hA;
    u8* h1q  = (u8*)hA;
    u8* h2q  = (u8*)hA;

    // one memset covers asnB, adnB, count (carved contiguously; each chunk 256-aligned)
    size_t zbytes = ((size_t)NN * 16 + 255 & ~(size_t)255) * 2 + (size_t)(NN + 8) * 4;
    hipMemsetAsync(asnB, 0, zbytes, stream);

    // CSR build
    hist_kernel<<<(EE + 255) / 256, 256, 0, stream>>>(dstv, count);
    scan1<<<NBLK, SCB, 0, stream>>>(count, excl, bsum);
    scan23<<<(NN + 256) / 256, 256, 0, stream>>>(excl, bsum, rowptr, cursor);
    scatter_kernel<<<(EPQ + 255) / 256, 256, 0, stream>>>(srcv, dstv, cursor, csrs);

    // weights + prep
    tcast_all<<<448, 256, 0, stream>>>(W0, W1, W2, W0t, W1t, W2t);
    prep_all<<<29, 1024, 0, stream>>>(g0, bt0, m0, v0, b0, g1, bt1, m1, v1, b1, W0t, W1t, W2t,
                                      as0, ad0, as1, ad1, as2w, ad2w, sc01, sh01, va0, va1, va2);

    const int MT = (NN + 127) / 128;   // 391
    const int NG = (NN + 3) / 4;       // 12500

    // Layer 0: cast+alpha; softmax+aggregate; block-diag GEMM + BN/ELU + L1-alpha (atomics)
    castx_alpha0<<<NG, 256, 0, stream>>>(x, va0, (u8*)xq, asnA, adnA);
    aggx<<<NG, 256, 0, stream>>>((const u8*)xq, asnA, adnA, rowptr, csrs, xa);
    gemm_t<128, true, true, 0, true><<<dim3(MT, 4), 256, 0, stream>>>(
        xa, 512, W0t, actB, 512, NN, 512, sc01, sh01, va1, asnB, adnB);

    // Layer 1: h1 = actB@W1 (fp8); softmax+gather + BN/ELU + L2-alpha (in-wave)
    gemm_t<512, false, false, 1, false><<<dim3(MT, 4), 256, 0, stream>>>(
        actB, 512, W1t, h1q, 512, NN, 512, nullptr, nullptr, nullptr, nullptr, nullptr);
    agg01<<<NG, 256, 0, stream>>>(h1q, asnB, adnB, rowptr, csrs, sc01 + 512, sh01 + 512, va2,
                                  actB, asnC, adnC);

    // Layer 2: h2 = actB@W2 (fp8, ldc=256); softmax+gather + final
    gemm_t<512, false, false, 1, false><<<dim3(MT, 2), 256, 0, stream>>>(
        actB, 512, W2t, h2q, 256, NN, 240, nullptr, nullptr, nullptr, nullptr, nullptr);
    agg2f<<<NG, 256, 0, stream>>>(h2q, asnC, adnC, rowptr, csrs, b2, out);
}

// Round 15
// 532.599 us; speedup vs baseline: 1.2282x; 1.2282x over previous
//
#include <hip/hip_runtime.h>
#include <cstdint>
#include <cstddef>

#define NN 50000
#define EE 800000
#define EPQ (EE + NN)
#define NEG_SLOPE 0.2f
#define BN_EPS 1e-5f
#define SCB 256
#define NBLK ((NN + SCB - 1) / SCB)

typedef _Float16 f16x8 __attribute__((ext_vector_type(8)));
typedef _Float16 f16x4 __attribute__((ext_vector_type(4)));
typedef _Float16 f16x2 __attribute__((ext_vector_type(2)));
typedef float f32x4 __attribute__((ext_vector_type(4)));
typedef float f32x2 __attribute__((ext_vector_type(2)));
typedef unsigned int u32;
typedef unsigned char u8;
typedef unsigned short u16;

static __device__ __forceinline__ float lrelu(float x) { return x > 0.f ? x : x * NEG_SLOPE; }
static __device__ __forceinline__ int rfl(int v) { return __builtin_amdgcn_readfirstlane(v); }

static __device__ __forceinline__ u8 f32_to_fp8(float v) {
    return (u8)(__builtin_amdgcn_cvt_pk_fp8_f32(v, v, 0, false) & 0xff);
}
static __device__ __forceinline__ void fp8x4_to_f32(u32 v, float* o) {
    f32x2 lo = __builtin_amdgcn_cvt_pk_f32_fp8(v, false);
    f32x2 hi = __builtin_amdgcn_cvt_pk_f32_fp8(v, true);
    o[0] = lo[0]; o[1] = lo[1]; o[2] = hi[0]; o[3] = hi[1];
}

static __device__ __forceinline__ void gld_lds16(const void* g, void* l) {
    __builtin_amdgcn_global_load_lds((const __attribute__((address_space(1))) u32*)g,
                                     (__attribute__((address_space(3))) u32*)l, 16, 0, 0);
}

// ---------------- CSR build ----------------
__global__ void hist_kernel(const int* __restrict__ dst, int* __restrict__ count) {
    int e = blockIdx.x * blockDim.x + threadIdx.x;
    if (e < EE) atomicAdd(&count[dst[e]], 1);
}

__global__ __launch_bounds__(SCB) void scan1(const int* __restrict__ count,
                                             int* __restrict__ excl, int* __restrict__ bsum) {
    __shared__ int tmp[SCB];
    int b = blockIdx.x, t = threadIdx.x;
    int i = b * SCB + t;
    int v = (i < NN) ? count[i] + 1 : 0;  // +1 self loop
    tmp[t] = v;
    __syncthreads();
    for (int off = 1; off < SCB; off <<= 1) {
        int u = (t >= off) ? tmp[t - off] : 0;
        __syncthreads();
        tmp[t] += u;
        __syncthreads();
    }
    if (i < NN) excl[i] = tmp[t] - v;
    if (t == SCB - 1) bsum[b] = tmp[t];
}

__global__ __launch_bounds__(256) void scan23(const int* __restrict__ excl,
                                              const int* __restrict__ bsum,
                                              int* __restrict__ rowptr, int* __restrict__ cursor) {
    __shared__ int pre[256];
    int t = threadIdx.x;
    int v = (t < NBLK) ? bsum[t] : 0;
    pre[t] = v;
    __syncthreads();
    for (int off = 1; off < 256; off <<= 1) {
        int u = (t >= off) ? pre[t - off] : 0;
        __syncthreads();
        pre[t] += u;
        __syncthreads();
    }
    int i = blockIdx.x * blockDim.x + t;
    if (i < NN) {
        int blk = i / SCB;
        int r = excl[i] + pre[blk] - ((blk < NBLK) ? bsum[blk] : 0);
        rowptr[i] = r;
        cursor[i] = r;
    }
    if (i == NN) rowptr[NN] = EPQ;
}

__global__ void scatter_kernel(const int* __restrict__ src, const int* __restrict__ dst,
                               int* __restrict__ cursor, int* __restrict__ csrs) {
    int e = blockIdx.x * blockDim.x + threadIdx.x;
    if (e < EE) {
        int d = dst[e];
        int slot = atomicAdd(&cursor[d], 1);
        csrs[slot] = src[e];
    } else if (e < EPQ) {
        int i = e - EE;
        int slot = atomicAdd(&cursor[i], 1);
        csrs[slot] = i;
    }
}

// ---------------- unified weight transpose+cast ----------------
__global__ __launch_bounds__(256) void tcast_all(const float* __restrict__ W0,
                                                 const float* __restrict__ W1,
                                                 const float* __restrict__ W2,
                                                 _Float16* __restrict__ W0t,
                                                 _Float16* __restrict__ W1t,
                                                 _Float16* __restrict__ W2t) {
    __shared__ float tile[32][33];
    int b = blockIdx.x;
    const float* W; _Float16* Wt; int K, Nc, bx, by;
    if (b < 64)       { W = W0; Wt = W0t; K = 128; Nc = 512; int q = b;       bx = q % 16, by = q / 16; }
    else if (b < 320) { W = W1; Wt = W1t; K = 512; Nc = 512; int q = b - 64;  bx = q % 16, by = q / 16; }
    else              { W = W2; Wt = W2t; K = 512; Nc = 240; int q = b - 320; bx = q % 8,  by = q / 8; }
    bx *= 32; by *= 32;
    int tx = threadIdx.x & 31, ty = threadIdx.x >> 5;
#pragma unroll
    for (int r = 0; r < 32; r += 8) {
        int k = by + ty + r, n = bx + tx;
        tile[ty + r][tx] = (k < K && n < Nc) ? W[(size_t)k * Nc + n] : 0.f;
    }
    __syncthreads();
#pragma unroll
    for (int r = 0; r < 32; r += 8) {
        int n = bx + ty + r, k = by + tx;
        if (n < Nc && k < K) Wt[(size_t)n * K + k] = (_Float16)tile[tx][ty + r];
    }
}

// ---------------- unified prep ----------------
__global__ __launch_bounds__(1024) void prep_all(const float* g0, const float* bt0,
                                                 const float* m0, const float* v0, const float* b0,
                                                 const float* g1, const float* bt1,
                                                 const float* m1, const float* v1, const float* b1,
                                                 const _Float16* __restrict__ W0t,
                                                 const _Float16* __restrict__ W1t,
                                                 const _Float16* __restrict__ W2t,
                                                 const float* __restrict__ as0,
                                                 const float* __restrict__ ad0,
                                                 const float* __restrict__ as1,
                                                 const float* __restrict__ ad1,
                                                 const float* __restrict__ as2,
                                                 const float* __restrict__ ad2,
                                                 float* sc01, float* sh01, float* va0, float* va1,
                                                 float* va2) {
    int bid = blockIdx.x, t = threadIdx.x;
    if (bid == 0) {
        const float *g, *bt, *m, *v, *b;
        int c;
        if (t < 512) { g = g0; bt = bt0; m = m0; v = v0; b = b0; c = t; }
        else         { g = g1; bt = bt1; m = m1; v = v1; b = b1; c = t - 512; }
        float s = g[c] * rsqrtf(v[c] + BN_EPS);
        sc01[t] = s;
        sh01[t] = (b[c] - m[c]) * s + bt[c];
        return;
    }
    int vb = bid - 1;
    if (vb < 8) {
        if (t >= 128) return;
        int j = vb, h = j & 3;
        const float* a = (j < 4 ? as0 : ad0) + h * 128;
        float s = 0.f;
        for (int c = 0; c < 128; c++) s += (float)W0t[(size_t)(h * 128 + c) * 128 + t] * a[c];
        va0[j * 128 + t] = s;
    } else if (vb < 16) {
        if (t >= 512) return;
        int j = vb - 8, h = j & 3;
        const float* a = (j < 4 ? as1 : ad1) + h * 128;
        float s = 0.f;
        for (int c = 0; c < 128; c++) s += (float)W1t[(size_t)(h * 128 + c) * 512 + t] * a[c];
        va1[j * 512 + t] = s;
    } else {
        if (t >= 512) return;
        int j = vb - 16, h = j % 6;
        const float* a = (j < 6 ? as2 : ad2) + h * 40;
        float s = 0.f;
        for (int c = 0; c < 40; c++) s += (float)W2t[(size_t)(h * 40 + c) * 512 + t] * a[c];
        va2[j * 512 + t] = s;
    }
}

// ---------------- fused: cast x -> fp8 table + L0 alpha dots ----------------
__global__ __launch_bounds__(256) void castx_alpha0(const float* __restrict__ x,
                                                    const float* __restrict__ va0,
                                                    u8* __restrict__ xq, float* __restrict__ asn,
                                                    float* __restrict__ adn) {
    int wid = threadIdx.x >> 6, lane = threadIdx.x & 63;
    int i = blockIdx.x * 4 + wid;
    if (i >= NN) return;
    f32x2 xv = *(const f32x2*)(x + (size_t)i * 128 + lane * 2);
    u32 q = __builtin_amdgcn_cvt_pk_fp8_f32(xv[0], xv[1], 0, false);
    *((u16*)(xq + (size_t)i * 128) + lane) = (u16)(q & 0xffff);
    float p[8];
#pragma unroll
    for (int j = 0; j < 8; j++) {
        f32x2 v = *(const f32x2*)(va0 + j * 128 + lane * 2);
        p[j] = xv[0] * v[0] + xv[1] * v[1];
    }
#pragma unroll
    for (int off = 32; off; off >>= 1)
#pragma unroll
        for (int j = 0; j < 8; j++) p[j] += __shfl_xor(p[j], off);
    if (lane == 0) {
        f32x4 o0 = {p[0], p[1], p[2], p[3]}, o1 = {p[4], p[5], p[6], p[7]};
        *(f32x4*)(asn + (size_t)i * 4) = o0;
        *(f32x4*)(adn + (size_t)i * 4) = o1;
    }
}

// ---------------- f16 MFMA GEMM; TK compile-time K ----------
template <int TK, bool BD, bool EPI, int OT>
__global__ __launch_bounds__(256) void gemm_t(const _Float16* __restrict__ A, int lda,
                                              const _Float16* __restrict__ Bt,
                                              void* __restrict__ Cv, int ldc, int M, int Nc,
                                              const float* __restrict__ sc,
                                              const float* __restrict__ sh) {
    __shared__ __align__(16) _Float16 As[2][128 * 64];
    __shared__ __align__(16) _Float16 Bs[2][128 * 64];
    const int t = threadIdx.x;
    const int bm = blockIdx.x * 128;
    const int bn = blockIdx.y * 128;
    const int wid = t >> 6, lane = t & 63;
    const int wm = (wid >> 1) * 64, wn = (wid & 1) * 64;
    const int aoff = BD ? bn : 0;
    f32x4 acc[4][4] = {};
    constexpr int nsteps = TK >> 6;

    auto STAGE = [&](int buf, int k0) {
#pragma unroll
        for (int it = 0; it < 4; ++it) {
            int rbase = it * 32 + wid * 8;
            int row = rbase + (lane >> 3);
            int c8g = (lane & 7) ^ (row & 7);
            gld_lds16(A + (size_t)(bm + row) * lda + aoff + k0 + c8g * 8,
                      (char*)As[buf] + rbase * 128);
            gld_lds16(Bt + (size_t)(bn + row) * TK + k0 + c8g * 8, (char*)Bs[buf] + rbase * 128);
        }
    };

    STAGE(0, 0);
    __syncthreads();
#pragma unroll
    for (int s = 0; s < nsteps; ++s) {
        const int cur = s & 1;
        if (s + 1 < nsteps) STAGE(cur ^ 1, (s + 1) * 64);
#pragma unroll
        for (int ks = 0; ks < 2; ++ks) {
            f16x8 af[4], bf[4];
#pragma unroll
            for (int mi = 0; mi < 4; ++mi) {
                int row = wm + mi * 16 + (lane & 15);
                int c8 = (ks * 4 + (lane >> 4)) ^ (row & 7);
                af[mi] = *(const f16x8*)((const char*)As[cur] + row * 128 + c8 * 16);
            }
#pragma unroll
            for (int ni = 0; ni < 4; ++ni) {
                int row = wn + ni * 16 + (lane & 15);
                int c8 = (ks * 4 + (lane >> 4)) ^ (row & 7);
                bf[ni] = *(const f16x8*)((const char*)Bs[cur] + row * 128 + c8 * 16);
            }
#pragma unroll
            for (int mi = 0; mi < 4; ++mi)
#pragma unroll
                for (int ni = 0; ni < 4; ++ni)
                    acc[mi][ni] = __builtin_amdgcn_mfma_f32_16x16x32_f16(af[mi], bf[ni],
                                                                         acc[mi][ni], 0, 0, 0);
        }
        __syncthreads();
    }
    float scv[4], shv[4];
    if (EPI) {
#pragma unroll
        for (int ni = 0; ni < 4; ++ni) {
            int gcol = bn + wn + ni * 16 + (lane & 15);
            scv[ni] = sc[gcol];
            shv[ni] = sh[gcol];
        }
    }
#pragma unroll
    for (int mi = 0; mi < 4; ++mi) {
#pragma unroll
        for (int r = 0; r < 4; ++r) {
            int grow = bm + wm + mi * 16 + (lane >> 4) * 4 + r;
            if (grow < M) {
#pragma unroll
                for (int ni = 0; ni < 4; ++ni) {
                    int gcol = bn + wn + ni * 16 + (lane & 15);
                    if (gcol < Nc) {
                        float v = acc[mi][ni][r];
                        if (EPI) {
                            v = v * scv[ni] + shv[ni];
                            v = v > 0.f ? v : expm1f(v);
                        }
                        if constexpr (OT == 0) {
                            ((_Float16*)Cv)[(size_t)grow * ldc + gcol] = (_Float16)v;
                        } else {
                            ((u8*)Cv)[(size_t)grow * ldc + gcol] = f32_to_fp8(v);
                        }
                    }
                }
            }
        }
    }
}

// ---------------- alpha L1 (standalone) ----------------
__global__ __launch_bounds__(256) void alpha1(const _Float16* __restrict__ feat,
                                              const float* __restrict__ va,
                                              float* __restrict__ asn, float* __restrict__ adn) {
    int wid = threadIdx.x >> 6, lane = threadIdx.x & 63;
    int i = blockIdx.x * 4 + wid;
    if (i >= NN) return;
    f16x8 x8 = *(const f16x8*)(feat + (size_t)i * 512 + lane * 8);
    float xf[8];
#pragma unroll
    for (int u = 0; u < 8; u++) xf[u] = (float)x8[u];
    float p[8];
#pragma unroll
    for (int j = 0; j < 8; j++) {
        const float* vr = va + j * 512 + lane * 8;
        f32x4 v0 = *(const f32x4*)vr;
        f32x4 v1 = *(const f32x4*)(vr + 4);
        p[j] = xf[0] * v0[0] + xf[1] * v0[1] + xf[2] * v0[2] + xf[3] * v0[3] +
               xf[4] * v1[0] + xf[5] * v1[1] + xf[6] * v1[2] + xf[7] * v1[3];
    }
#pragma unroll
    for (int off = 32; off; off >>= 1)
#pragma unroll
        for (int j = 0; j < 8; j++) p[j] += __shfl_xor(p[j], off);
    if (lane == 0) {
        f32x4 o0 = {p[0], p[1], p[2], p[3]}, o1 = {p[4], p[5], p[6], p[7]};
        *(f32x4*)(asn + (size_t)i * 4) = o0;
        *(f32x4*)(adn + (size_t)i * 4) = o1;
    }
}

// ---------------- L0: fused softmax + x-space aggregation (fp8 x, 4-edge unroll) ----------
__global__ __launch_bounds__(256) void aggx(const u8* __restrict__ xq,
                                            const float* __restrict__ asn,
                                            const float* __restrict__ adn,
                                            const int* __restrict__ rowptr,
                                            const int* __restrict__ csr,
                                            _Float16* __restrict__ xa) {
    __shared__ __align__(8) _Float16 wsl[4][64][4];
    int wid = threadIdx.x >> 6, lane = threadIdx.x & 63;
    int i = blockIdx.x * 4 + wid;
    if (i >= NN) return;
    int start = rfl(rowptr[i]), end = rfl(rowptr[i + 1]);
    int deg = end - start;
    bool fastp = deg <= 64;
    f32x4 ad = *(const f32x4*)(adn + (size_t)i * 4);
    f32x4 m4, rd4;
    if (fastp) {
        bool v = lane < deg;
        int e = start + (v ? lane : 0);
        int s = csr[e];
        f32x4 a = *(const f32x4*)(asn + (size_t)s * 4);
        f32x4 sc4, mm, wv, dn;
#pragma unroll
        for (int j = 0; j < 4; j++) { sc4[j] = v ? lrelu(a[j] + ad[j]) : -1e30f; mm[j] = sc4[j]; }
#pragma unroll
        for (int off = 32; off; off >>= 1)
#pragma unroll
            for (int j = 0; j < 4; j++) mm[j] = fmaxf(mm[j], __shfl_xor(mm[j], off));
#pragma unroll
        for (int j = 0; j < 4; j++) { wv[j] = v ? __expf(sc4[j] - mm[j]) : 0.f; dn[j] = wv[j]; }
#pragma unroll
        for (int off = 32; off; off >>= 1)
#pragma unroll
            for (int j = 0; j < 4; j++) dn[j] += __shfl_xor(dn[j], off);
        f16x4 o;
#pragma unroll
        for (int j = 0; j < 4; j++) o[j] = (_Float16)(wv[j] / (dn[j] + 1e-16f));
        *(f16x4*)&wsl[wid][lane][0] = o;
    } else {
        f32x4 mm = {-1e30f, -1e30f, -1e30f, -1e30f};
        for (int e = start + lane; e < end; e += 64) {
            int s = csr[e];
            f32x4 a = *(const f32x4*)(asn + (size_t)s * 4);
#pragma unroll
            for (int j = 0; j < 4; j++) mm[j] = fmaxf(mm[j], lrelu(a[j] + ad[j]));
        }
#pragma unroll
        for (int off = 32; off; off >>= 1)
#pragma unroll
            for (int j = 0; j < 4; j++) mm[j] = fmaxf(mm[j], __shfl_xor(mm[j], off));
        f32x4 dn = {0.f, 0.f, 0.f, 0.f};
        for (int e = start + lane; e < end; e += 64) {
            int s = csr[e];
            f32x4 a = *(const f32x4*)(asn + (size_t)s * 4);
#pragma unroll
            for (int j = 0; j < 4; j++) dn[j] += __expf(lrelu(a[j] + ad[j]) - mm[j]);
        }
#pragma unroll
        for (int off = 32; off; off >>= 1)
#pragma unroll
            for (int j = 0; j < 4; j++) dn[j] += __shfl_xor(dn[j], off);
        m4 = mm;
#pragma unroll
        for (int j = 0; j < 4; j++) rd4[j] = 1.f / (dn[j] + 1e-16f);
    }
    const char* xb = (const char*)xq + lane * 2;
    float acc[8] = {};
    int e = start;
    auto getw = [&](int ee, int ss, float* w) {
        if (fastp) {
            f16x4 wv4 = *(const f16x4*)&wsl[wid][ee - start][0];
#pragma unroll
            for (int h = 0; h < 4; h++) w[h] = (float)wv4[h];
        } else {
#pragma unroll
            for (int h = 0; h < 4; h++)
                w[h] = __expf(lrelu(asn[(size_t)ss * 4 + h] + ad[h]) - m4[h]) * rd4[h];
        }
    };
    for (; e + 4 <= end; e += 4) {
        int4 sv = *(const int4*)(csr + e);
        int s0 = rfl(sv.x), s1 = rfl(sv.y), s2 = rfl(sv.z), s3 = rfl(sv.w);
        u16 pv0 = *(const u16*)(xb + (u32)s0 * 128u);
        u16 pv1 = *(const u16*)(xb + (u32)s1 * 128u);
        u16 pv2 = *(const u16*)(xb + (u32)s2 * 128u);
        u16 pv3 = *(const u16*)(xb + (u32)s3 * 128u);
        float w0[4], w1[4], w2[4], w3[4];
        getw(e, s0, w0); getw(e + 1, s1, w1); getw(e + 2, s2, w2); getw(e + 3, s3, w3);
        f32x2 q0 = __builtin_amdgcn_cvt_pk_f32_fp8((u32)pv0, false);
        f32x2 q1 = __builtin_amdgcn_cvt_pk_f32_fp8((u32)pv1, false);
        f32x2 q2 = __builtin_amdgcn_cvt_pk_f32_fp8((u32)pv2, false);
        f32x2 q3 = __builtin_amdgcn_cvt_pk_f32_fp8((u32)pv3, false);
#pragma unroll
        for (int h = 0; h < 4; h++) {
            acc[h * 2]     += w0[h] * q0[0] + w1[h] * q1[0] + w2[h] * q2[0] + w3[h] * q3[0];
            acc[h * 2 + 1] += w0[h] * q0[1] + w1[h] * q1[1] + w2[h] * q2[1] + w3[h] * q3[1];
        }
    }
    for (; e < end; e++) {
        int s = rfl(csr[e]);
        float w[4];
        getw(e, s, w);
        u16 pv = *(const u16*)(xb + (u32)s * 128u);
        f32x2 q = __builtin_amdgcn_cvt_pk_f32_fp8((u32)pv, false);
#pragma unroll
        for (int h = 0; h < 4; h++) {
            acc[h * 2] += w[h] * q[0];
            acc[h * 2 + 1] += w[h] * q[1];
        }
    }
#pragma unroll
    for (int h = 0; h < 4; h++) {
        f16x2 o;
        o[0] = (_Float16)acc[h * 2];
        o[1] = (_Float16)acc[h * 2 + 1];
        *(f16x2*)(xa + (size_t)i * 512 + h * 128 + lane * 2) = o;
    }
}

// ---------------- L1: fused softmax + fp8 gather + BN/ELU + L2 alpha dots (in-wave) -------
__global__ __launch_bounds__(256) void agg01(const u8* __restrict__ h,
                                             const float* __restrict__ asn,
                                             const float* __restrict__ adn,
                                             const int* __restrict__ rowptr,
                                             const int* __restrict__ csr,
                                             const float* __restrict__ sc,
                                             const float* __restrict__ sh,
                                             const float* __restrict__ va2,
                                             _Float16* __restrict__ out,
                                             float* __restrict__ asnC,
                                             float* __restrict__ adnC) {
    __shared__ __align__(8) _Float16 wsl[4][64][4];
    int wid = threadIdx.x >> 6, lane = threadIdx.x & 63;
    int i = blockIdx.x * 4 + wid;
    if (i >= NN) return;
    int start = rfl(rowptr[i]), end = rfl(rowptr[i + 1]);
    int deg = end - start;
    bool fastp = deg <= 64;
    f32x4 ad = *(const f32x4*)(adn + (size_t)i * 4);
    f32x4 m4, rd4;
    if (fastp) {
        bool v = lane < deg;
        int e = start + (v ? lane : 0);
        int s = csr[e];
        f32x4 a = *(const f32x4*)(asn + (size_t)s * 4);
        f32x4 sc4, mm, wv, dn;
#pragma unroll
        for (int j = 0; j < 4; j++) { sc4[j] = v ? lrelu(a[j] + ad[j]) : -1e30f; mm[j] = sc4[j]; }
#pragma unroll
        for (int off = 32; off; off >>= 1)
#pragma unroll
            for (int j = 0; j < 4; j++) mm[j] = fmaxf(mm[j], __shfl_xor(mm[j], off));
#pragma unroll
        for (int j = 0; j < 4; j++) { wv[j] = v ? __expf(sc4[j] - mm[j]) : 0.f; dn[j] = wv[j]; }
#pragma unroll
        for (int off = 32; off; off >>= 1)
#pragma unroll
            for (int j = 0; j < 4; j++) dn[j] += __shfl_xor(dn[j], off);
        f16x4 o;
#pragma unroll
        for (int j = 0; j < 4; j++) o[j] = (_Float16)(wv[j] / (dn[j] + 1e-16f));
        *(f16x4*)&wsl[wid][lane][0] = o;
    } else {
        f32x4 mm = {-1e30f, -1e30f, -1e30f, -1e30f};
        for (int e = start + lane; e < end; e += 64) {
            int s = csr[e];
            f32x4 a = *(const f32x4*)(asn + (size_t)s * 4);
#pragma unroll
            for (int j = 0; j < 4; j++) mm[j] = fmaxf(mm[j], lrelu(a[j] + ad[j]));
        }
#pragma unroll
        for (int off = 32; off; off >>= 1)
#pragma unroll
            for (int j = 0; j < 4; j++) mm[j] = fmaxf(mm[j], __shfl_xor(mm[j], off));
        f32x4 dn = {0.f, 0.f, 0.f, 0.f};
        for (int e = start + lane; e < end; e += 64) {
            int s = csr[e];
            f32x4 a = *(const f32x4*)(asn + (size_t)s * 4);
#pragma unroll
            for (int j = 0; j < 4; j++) dn[j] += __expf(lrelu(a[j] + ad[j]) - mm[j]);
        }
#pragma unroll
        for (int off = 32; off; off >>= 1)
#pragma unroll
            for (int j = 0; j < 4; j++) dn[j] += __shfl_xor(dn[j], off);
        m4 = mm;
#pragma unroll
        for (int j = 0; j < 4; j++) rd4[j] = 1.f / (dn[j] + 1e-16f);
    }
    int head = lane >> 4;
    const char* hb = (const char*)h + lane * 8;
    float acc0[8] = {}, acc1[8] = {};
    int e = start;
    for (; e + 2 <= end; e += 2) {
        int2 sv = *(const int2*)(csr + e);
        int s0 = rfl(sv.x), s1 = rfl(sv.y);
        float w0, w1;
        if (fastp) {
            w0 = (float)wsl[wid][e - start][head];
            w1 = (float)wsl[wid][e + 1 - start][head];
        } else {
            w0 = __expf(lrelu(asn[(size_t)s0 * 4 + head] + ad[head]) - m4[head]) * rd4[head];
            w1 = __expf(lrelu(asn[(size_t)s1 * 4 + head] + ad[head]) - m4[head]) * rd4[head];
        }
        uint2 p0 = *(const uint2*)(hb + (u32)s0 * 512u);
        uint2 p1 = *(const uint2*)(hb + (u32)s1 * 512u);
        float q0[8], q1[8];
        fp8x4_to_f32(p0.x, q0); fp8x4_to_f32(p0.y, q0 + 4);
        fp8x4_to_f32(p1.x, q1); fp8x4_to_f32(p1.y, q1 + 4);
#pragma unroll
        for (int j = 0; j < 8; j++) {
            acc0[j] += w0 * q0[j];
            acc1[j] += w1 * q1[j];
        }
    }
    if (e < end) {
        int s0 = rfl(csr[e]);
        float w0;
        if (fastp) w0 = (float)wsl[wid][e - start][head];
        else w0 = __expf(lrelu(asn[(size_t)s0 * 4 + head] + ad[head]) - m4[head]) * rd4[head];
        uint2 p0 = *(const uint2*)(hb + (u32)s0 * 512u);
        float q0[8];
        fp8x4_to_f32(p0.x, q0); fp8x4_to_f32(p0.y, q0 + 4);
#pragma unroll
        for (int j = 0; j < 8; j++) acc0[j] += w0 * q0[j];
    }
    int ch = lane * 8;
    f32x4 sc0 = *(const f32x4*)(sc + ch), sc1 = *(const f32x4*)(sc + ch + 4);
    f32x4 sh0 = *(const f32x4*)(sh + ch), sh1 = *(const f32x4*)(sh + ch + 4);
    f16x8 o;
    float valf[8];
#pragma unroll
    for (int j = 0; j < 8; j++) {
        float s = (j < 4) ? sc0[j] : sc1[j - 4];
        float b = (j < 4) ? sh0[j] : sh1[j - 4];
        float val = (acc0[j] + acc1[j]) * s + b;
        val = val > 0.f ? val : expm1f(val);
        valf[j] = val;
        o[j] = (_Float16)val;
    }
    *(f16x8*)(out + (size_t)i * 512 + ch) = o;
    // L2 alpha dots: full row is in this wave
    float pj[12];
#pragma unroll
    for (int j = 0; j < 12; j++) {
        const float* vr = va2 + j * 512 + ch;
        f32x4 v0 = *(const f32x4*)vr;
        f32x4 v1 = *(const f32x4*)(vr + 4);
        pj[j] = valf[0] * v0[0] + valf[1] * v0[1] + valf[2] * v0[2] + valf[3] * v0[3] +
                valf[4] * v1[0] + valf[5] * v1[1] + valf[6] * v1[2] + valf[7] * v1[3];
    }
#pragma unroll
    for (int off = 32; off; off >>= 1)
#pragma unroll
        for (int j = 0; j < 12; j++) pj[j] += __shfl_xor(pj[j], off);
    if (lane == 0) {
#pragma unroll
        for (int hh = 0; hh < 6; hh++) {
            asnC[(size_t)i * 8 + hh] = pj[hh];
            adnC[(size_t)i * 8 + hh] = pj[6 + hh];
        }
    }
}

// ---------------- L2: fused softmax (6 heads) + fp8 gather (4-edge) + log_softmax ----------
__global__ __launch_bounds__(256) void agg2f(const u8* __restrict__ h2,
                                             const float* __restrict__ asn,
                                             const float* __restrict__ adn,
                                             const int* __restrict__ rowptr,
                                             const int* __restrict__ csr,
                                             const float* __restrict__ b2,
                                             float* __restrict__ out) {
    __shared__ __align__(16) _Float16 wsl[4][64][8];
    __shared__ float sval[4][240];
    int wid = threadIdx.x >> 6, lane = threadIdx.x & 63;
    int i = blockIdx.x * 4 + wid;
    if (i < NN) {
        int start = rfl(rowptr[i]), end = rfl(rowptr[i + 1]);
        int deg = end - start;
        bool fastp = deg <= 64;
        f32x4 ad0 = *(const f32x4*)(adn + (size_t)i * 8);
        f32x4 ad1 = *(const f32x4*)(adn + (size_t)i * 8 + 4);
        float adh[6] = {ad0[0], ad0[1], ad0[2], ad0[3], ad1[0], ad1[1]};
        float m6[6], rd6[6];
        if (fastp) {
            bool v = lane < deg;
            int e = start + (v ? lane : 0);
            int s = csr[e];
            f32x4 x0 = *(const f32x4*)(asn + (size_t)s * 8);
            f32x4 x1 = *(const f32x4*)(asn + (size_t)s * 8 + 4);
            float av[6] = {x0[0], x0[1], x0[2], x0[3], x1[0], x1[1]};
            float sc6[6], mm[6], wv[6], dn[6];
#pragma unroll
            for (int j = 0; j < 6; j++) {
                sc6[j] = v ? lrelu(av[j] + adh[j]) : -1e30f;
                mm[j] = sc6[j];
            }
#pragma unroll
            for (int off = 32; off; off >>= 1)
#pragma unroll
                for (int j = 0; j < 6; j++) mm[j] = fmaxf(mm[j], __shfl_xor(mm[j], off));
#pragma unroll
            for (int j = 0; j < 6; j++) { wv[j] = v ? __expf(sc6[j] - mm[j]) : 0.f; dn[j] = wv[j]; }
#pragma unroll
            for (int off = 32; off; off >>= 1)
#pragma unroll
                for (int j = 0; j < 6; j++) dn[j] += __shfl_xor(dn[j], off);
            f16x8 o;
#pragma unroll
            for (int j = 0; j < 6; j++) o[j] = (_Float16)(wv[j] / (dn[j] + 1e-16f));
            o[6] = (_Float16)0.f;
            o[7] = (_Float16)0.f;
            *(f16x8*)&wsl[wid][lane][0] = o;
        } else {
            float mm[6], dn[6];
#pragma unroll
            for (int j = 0; j < 6; j++) { mm[j] = -1e30f; dn[j] = 0.f; }
            for (int e = start + lane; e < end; e += 64) {
                int s = csr[e];
                f32x4 x0 = *(const f32x4*)(asn + (size_t)s * 8);
                f32x4 x1 = *(const f32x4*)(asn + (size_t)s * 8 + 4);
                float av[6] = {x0[0], x0[1], x0[2], x0[3], x1[0], x1[1]};
#pragma unroll
                for (int j = 0; j < 6; j++) mm[j] = fmaxf(mm[j], lrelu(av[j] + adh[j]));
            }
#pragma unroll
            for (int off = 32; off; off >>= 1)
#pragma unroll
                for (int j = 0; j < 6; j++) mm[j] = fmaxf(mm[j], __shfl_xor(mm[j], off));
            for (int e = start + lane; e < end; e += 64) {
                int s = csr[e];
                f32x4 x0 = *(const f32x4*)(asn + (size_t)s * 8);
                f32x4 x1 = *(const f32x4*)(asn + (size_t)s * 8 + 4);
                float av[6] = {x0[0], x0[1], x0[2], x0[3], x1[0], x1[1]};
#pragma unroll
                for (int j = 0; j < 6; j++) dn[j] += __expf(lrelu(av[j] + adh[j]) - mm[j]);
            }
#pragma unroll
            for (int off = 32; off; off >>= 1)
#pragma unroll
                for (int j = 0; j < 6; j++) dn[j] += __shfl_xor(dn[j], off);
#pragma unroll
            for (int j = 0; j < 6; j++) { m6[j] = mm[j]; rd6[j] = 1.f / (dn[j] + 1e-16f); }
        }
        int head = (lane < 60) ? (lane / 10) : 0;
        const char* hb = (const char*)h2 + lane * 4;
        float a0[4] = {}, a1[4] = {};
        int e = start;
        auto getw1 = [&](int ee, int ss) -> float {
            if (fastp) return (float)wsl[wid][ee - start][head];
            return __expf(lrelu(asn[(size_t)ss * 8 + head] + adh[head]) - m6[head]) * rd6[head];
        };
        for (; e + 4 <= end; e += 4) {
            int4 sv = *(const int4*)(csr + e);
            int s0 = rfl(sv.x), s1 = rfl(sv.y), s2 = rfl(sv.z), s3 = rfl(sv.w);
            u32 p0 = *(const u32*)(hb + (u32)s0 * 256u);
            u32 p1 = *(const u32*)(hb + (u32)s1 * 256u);
            u32 p2 = *(const u32*)(hb + (u32)s2 * 256u);
            u32 p3 = *(const u32*)(hb + (u32)s3 * 256u);
            float w0 = getw1(e, s0), w1 = getw1(e + 1, s1);
            float w2 = getw1(e + 2, s2), w3 = getw1(e + 3, s3);
            float q0[4], q1[4], q2[4], q3[4];
            fp8x4_to_f32(p0, q0);
            fp8x4_to_f32(p1, q1);
            fp8x4_to_f32(p2, q2);
            fp8x4_to_f32(p3, q3);
#pragma unroll
            for (int j = 0; j < 4; j++) {
                a0[j] += w0 * q0[j] + w2 * q2[j];
                a1[j] += w1 * q1[j] + w3 * q3[j];
            }
        }
        for (; e < end; e++) {
            int s0 = rfl(csr[e]);
            float w0 = getw1(e, s0);
            u32 p0 = *(const u32*)(hb + (u32)s0 * 256u);
            float q0[4];
            fp8x4_to_f32(p0, q0);
#pragma unroll
            for (int j = 0; j < 4; j++) a0[j] += w0 * q0[j];
        }
        if (lane < 60) {
#pragma unroll
            for (int j = 0; j < 4; j++) sval[wid][lane * 4 + j] = a0[j] + a1[j];
        }
    }
    __syncthreads();
    if (i < NN) {
        float v = -INFINITY;
        if (lane < 40) {
            float s = 0.f;
#pragma unroll
            for (int hh = 0; hh < 6; hh++) s += sval[wid][hh * 40 + lane];
            v = s * (1.0f / 6.0f) + b2[lane];
        }
        float mm = v;
#pragma unroll
        for (int off = 32; off; off >>= 1) mm = fmaxf(mm, __shfl_xor(mm, off));
        float se = (lane < 40) ? __expf(v - mm) : 0.f;
#pragma unroll
        for (int off = 32; off; off >>= 1) se += __shfl_xor(se, off);
        if (lane < 40) out[(size_t)i * 40 + lane] = v - mm - logf(se);
    }
}

extern "C" void kernel_launch(void* const* d_in, const int* in_sizes, int n_in,
                              void* d_out, int out_size, void* d_ws, size_t ws_size,
                              hipStream_t stream) {
    const float* x   = (const float*)d_in[0];
    const int*   ei  = (const int*)d_in[1];
    const float* W0  = (const float*)d_in[2];
    const float* as0 = (const float*)d_in[3];
    const float* ad0 = (const float*)d_in[4];
    const float* b0  = (const float*)d_in[5];
    const float* g0  = (const float*)d_in[6];
    const float* bt0 = (const float*)d_in[7];
    const float* m0  = (const float*)d_in[8];
    const float* v0  = (const float*)d_in[9];
    const float* W1  = (const float*)d_in[10];
    const float* as1 = (const float*)d_in[11];
    const float* ad1 = (const float*)d_in[12];
    const float* b1  = (const float*)d_in[13];
    const float* g1  = (const float*)d_in[14];
    const float* bt1 = (const float*)d_in[15];
    const float* m1  = (const float*)d_in[16];
    const float* v1  = (const float*)d_in[17];
    const float* W2  = (const float*)d_in[18];
    const float* as2w = (const float*)d_in[19];
    const float* ad2w = (const float*)d_in[20];
    const float* b2  = (const float*)d_in[21];
    float* out = (float*)d_out;
    const int* srcv = ei;
    const int* dstv = ei + EE;

    char* w = (char*)d_ws;
    auto carve = [&](size_t bytes) {
        char* p = w;
        w += (bytes + 255) & ~(size_t)255;
        return p;
    };
    u32* xq        = (u32*)carve((size_t)NN * 128);
    _Float16* hA   = (_Float16*)carve((size_t)NN * 512 * 2);
    _Float16* actB = (_Float16*)carve((size_t)NN * 512 * 2);
    _Float16* W0t  = (_Float16*)carve((size_t)512 * 128 * 2);
    _Float16* W1t  = (_Float16*)carve((size_t)512 * 512 * 2);
    _Float16* W2t  = (_Float16*)carve((size_t)240 * 512 * 2);
    float* va0  = (float*)carve((size_t)8 * 128 * 4);
    float* va1  = (float*)carve((size_t)8 * 512 * 4);
    float* va2  = (float*)carve((size_t)12 * 512 * 4);
    float* sc01 = (float*)carve((size_t)1024 * 4);
    float* sh01 = (float*)carve((size_t)1024 * 4);
    float* asnA = (float*)carve((size_t)NN * 4 * 4);
    float* adnA = (float*)carve((size_t)NN * 4 * 4);
    float* asnB = (float*)carve((size_t)NN * 4 * 4);
    float* adnB = (float*)carve((size_t)NN * 4 * 4);
    float* asnC = (float*)carve((size_t)NN * 8 * 4);
    float* adnC = (float*)carve((size_t)NN * 8 * 4);
    int* count  = (int*)carve((size_t)(NN + 8) * 4);
    int* excl   = (int*)carve((size_t)(NN + 8) * 4);
    int* bsum   = (int*)carve((size_t)512 * 4);
    int* rowptr = (int*)carve((size_t)(NN + 8) * 4);
    int* cursor = (int*)carve((size_t)(NN + 8) * 4);
    int* csrs   = (int*)carve((size_t)(EPQ + 8) * 4);
    _Float16* xa = hA;
    u8* h1q  = (u8*)hA;
    u8* h2q  = (u8*)hA;

    // CSR build
    hipMemsetAsync(count, 0, (size_t)NN * 4, stream);
    hist_kernel<<<(EE + 255) / 256, 256, 0, stream>>>(dstv, count);
    scan1<<<NBLK, SCB, 0, stream>>>(count, excl, bsum);
    scan23<<<(NN + 256) / 256, 256, 0, stream>>>(excl, bsum, rowptr, cursor);
    scatter_kernel<<<(EPQ + 255) / 256, 256, 0, stream>>>(srcv, dstv, cursor, csrs);

    // weights + prep
    tcast_all<<<448, 256, 0, stream>>>(W0, W1, W2, W0t, W1t, W2t);
    prep_all<<<29, 1024, 0, stream>>>(g0, bt0, m0, v0, b0, g1, bt1, m1, v1, b1, W0t, W1t, W2t,
                                      as0, ad0, as1, ad1, as2w, ad2w, sc01, sh01, va0, va1, va2);

    const int MT = (NN + 127) / 128;   // 391
    const int NG = (NN + 3) / 4;       // 12500

    // Layer 0
    castx_alpha0<<<NG, 256, 0, stream>>>(x, va0, (u8*)xq, asnA, adnA);
    aggx<<<NG, 256, 0, stream>>>((const u8*)xq, asnA, adnA, rowptr, csrs, xa);
    gemm_t<128, true, true, 0><<<dim3(MT, 4), 256, 0, stream>>>(xa, 512, W0t, actB, 512, NN, 512,
                                                                sc01, sh01);

    // Layer 1
    gemm_t<512, false, false, 1><<<dim3(MT, 4), 256, 0, stream>>>(actB, 512, W1t, h1q, 512, NN,
                                                                  512, nullptr, nullptr);
    alpha1<<<NG, 256, 0, stream>>>(actB, va1, asnB, adnB);
    agg01<<<NG, 256, 0, stream>>>(h1q, asnB, adnB, rowptr, csrs, sc01 + 512, sh01 + 512, va2,
                                  actB, asnC, adnC);

    // Layer 2
    gemm_t<512, false, false, 1><<<dim3(MT, 2), 256, 0, stream>>>(actB, 512, W2t, h2q, 256, NN,
                                                                  240, nullptr, nullptr);
    agg2f<<<NG, 256, 0, stream>>>(h2q, asnC, adnC, rowptr, csrs, b2, out);
}

// Round 16
// 525.608 us; speedup vs baseline: 1.2445x; 1.0133x over previous
//
#include <hip/hip_runtime.h>
#include <cstdint>
#include <cstddef>

#define NN 50000
#define EE 800000
#define EPQ (EE + NN)
#define NEG_SLOPE 0.2f
#define BN_EPS 1e-5f
#define SCB 256
#define NBLK ((NN + SCB - 1) / SCB)

typedef _Float16 f16x8 __attribute__((ext_vector_type(8)));
typedef _Float16 f16x4 __attribute__((ext_vector_type(4)));
typedef _Float16 f16x2 __attribute__((ext_vector_type(2)));
typedef float f32x4 __attribute__((ext_vector_type(4)));
typedef float f32x2 __attribute__((ext_vector_type(2)));
typedef unsigned int u32;
typedef unsigned char u8;
typedef unsigned short u16;

static __device__ __forceinline__ float lrelu(float x) { return x > 0.f ? x : x * NEG_SLOPE; }
static __device__ __forceinline__ int rfl(int v) { return __builtin_amdgcn_readfirstlane(v); }

static __device__ __forceinline__ u8 f32_to_fp8(float v) {
    return (u8)(__builtin_amdgcn_cvt_pk_fp8_f32(v, v, 0, false) & 0xff);
}
static __device__ __forceinline__ void fp8x4_to_f32(u32 v, float* o) {
    f32x2 lo = __builtin_amdgcn_cvt_pk_f32_fp8(v, false);
    f32x2 hi = __builtin_amdgcn_cvt_pk_f32_fp8(v, true);
    o[0] = lo[0]; o[1] = lo[1]; o[2] = hi[0]; o[3] = hi[1];
}

static __device__ __forceinline__ void gld_lds16(const void* g, void* l) {
    __builtin_amdgcn_global_load_lds((const __attribute__((address_space(1))) u32*)g,
                                     (__attribute__((address_space(3))) u32*)l, 16, 0, 0);
}

// ---------------- CSR build ----------------
__global__ void hist_kernel(const int* __restrict__ dst, int* __restrict__ count) {
    int e = blockIdx.x * blockDim.x + threadIdx.x;
    if (e < EE) atomicAdd(&count[dst[e]], 1);
}

__global__ __launch_bounds__(SCB) void scan1(const int* __restrict__ count,
                                             int* __restrict__ excl, int* __restrict__ bsum) {
    __shared__ int tmp[SCB];
    int b = blockIdx.x, t = threadIdx.x;
    int i = b * SCB + t;
    int v = (i < NN) ? count[i] + 1 : 0;  // +1 self loop
    tmp[t] = v;
    __syncthreads();
    for (int off = 1; off < SCB; off <<= 1) {
        int u = (t >= off) ? tmp[t - off] : 0;
        __syncthreads();
        tmp[t] += u;
        __syncthreads();
    }
    if (i < NN) excl[i] = tmp[t] - v;
    if (t == SCB - 1) bsum[b] = tmp[t];
}

__global__ __launch_bounds__(256) void scan23(const int* __restrict__ excl,
                                              const int* __restrict__ bsum,
                                              int* __restrict__ rowptr, int* __restrict__ cursor) {
    __shared__ int pre[256];
    int t = threadIdx.x;
    int v = (t < NBLK) ? bsum[t] : 0;
    pre[t] = v;
    __syncthreads();
    for (int off = 1; off < 256; off <<= 1) {
        int u = (t >= off) ? pre[t - off] : 0;
        __syncthreads();
        pre[t] += u;
        __syncthreads();
    }
    int i = blockIdx.x * blockDim.x + t;
    if (i < NN) {
        int blk = i / SCB;
        int r = excl[i] + pre[blk] - ((blk < NBLK) ? bsum[blk] : 0);
        rowptr[i] = r;
        cursor[i] = r;
    }
    if (i == NN) rowptr[NN] = EPQ;
}

__global__ void scatter_kernel(const int* __restrict__ src, const int* __restrict__ dst,
                               int* __restrict__ cursor, int* __restrict__ csrs) {
    int e = blockIdx.x * blockDim.x + threadIdx.x;
    if (e < EE) {
        int d = dst[e];
        int slot = atomicAdd(&cursor[d], 1);
        csrs[slot] = src[e];
    } else if (e < EPQ) {
        int i = e - EE;
        int slot = atomicAdd(&cursor[i], 1);
        csrs[slot] = i;
    }
}

// ---------------- unified weight transpose+cast ----------------
__global__ __launch_bounds__(256) void tcast_all(const float* __restrict__ W0,
                                                 const float* __restrict__ W1,
                                                 const float* __restrict__ W2,
                                                 _Float16* __restrict__ W0t,
                                                 _Float16* __restrict__ W1t,
                                                 _Float16* __restrict__ W2t) {
    __shared__ float tile[32][33];
    int b = blockIdx.x;
    const float* W; _Float16* Wt; int K, Nc, bx, by;
    if (b < 64)       { W = W0; Wt = W0t; K = 128; Nc = 512; int q = b;       bx = q % 16, by = q / 16; }
    else if (b < 320) { W = W1; Wt = W1t; K = 512; Nc = 512; int q = b - 64;  bx = q % 16, by = q / 16; }
    else              { W = W2; Wt = W2t; K = 512; Nc = 240; int q = b - 320; bx = q % 8,  by = q / 8; }
    bx *= 32; by *= 32;
    int tx = threadIdx.x & 31, ty = threadIdx.x >> 5;
#pragma unroll
    for (int r = 0; r < 32; r += 8) {
        int k = by + ty + r, n = bx + tx;
        tile[ty + r][tx] = (k < K && n < Nc) ? W[(size_t)k * Nc + n] : 0.f;
    }
    __syncthreads();
#pragma unroll
    for (int r = 0; r < 32; r += 8) {
        int n = bx + ty + r, k = by + tx;
        if (n < Nc && k < K) Wt[(size_t)n * K + k] = (_Float16)tile[tx][ty + r];
    }
}

// ---------------- unified prep ----------------
__global__ __launch_bounds__(1024) void prep_all(const float* g0, const float* bt0,
                                                 const float* m0, const float* v0, const float* b0,
                                                 const float* g1, const float* bt1,
                                                 const float* m1, const float* v1, const float* b1,
                                                 const _Float16* __restrict__ W0t,
                                                 const _Float16* __restrict__ W1t,
                                                 const _Float16* __restrict__ W2t,
                                                 const float* __restrict__ as0,
                                                 const float* __restrict__ ad0,
                                                 const float* __restrict__ as1,
                                                 const float* __restrict__ ad1,
                                                 const float* __restrict__ as2,
                                                 const float* __restrict__ ad2,
                                                 float* sc01, float* sh01, float* va0, float* va1,
                                                 float* va2) {
    int bid = blockIdx.x, t = threadIdx.x;
    if (bid == 0) {
        const float *g, *bt, *m, *v, *b;
        int c;
        if (t < 512) { g = g0; bt = bt0; m = m0; v = v0; b = b0; c = t; }
        else         { g = g1; bt = bt1; m = m1; v = v1; b = b1; c = t - 512; }
        float s = g[c] * rsqrtf(v[c] + BN_EPS);
        sc01[t] = s;
        sh01[t] = (b[c] - m[c]) * s + bt[c];
        return;
    }
    int vb = bid - 1;
    if (vb < 8) {
        if (t >= 128) return;
        int j = vb, h = j & 3;
        const float* a = (j < 4 ? as0 : ad0) + h * 128;
        float s = 0.f;
        for (int c = 0; c < 128; c++) s += (float)W0t[(size_t)(h * 128 + c) * 128 + t] * a[c];
        va0[j * 128 + t] = s;
    } else if (vb < 16) {
        if (t >= 512) return;
        int j = vb - 8, h = j & 3;
        const float* a = (j < 4 ? as1 : ad1) + h * 128;
        float s = 0.f;
        for (int c = 0; c < 128; c++) s += (float)W1t[(size_t)(h * 128 + c) * 512 + t] * a[c];
        va1[j * 512 + t] = s;
    } else {
        if (t >= 512) return;
        int j = vb - 16, h = j % 6;
        const float* a = (j < 6 ? as2 : ad2) + h * 40;
        float s = 0.f;
        for (int c = 0; c < 40; c++) s += (float)W2t[(size_t)(h * 40 + c) * 512 + t] * a[c];
        va2[j * 512 + t] = s;
    }
}

// ---------------- fused: cast x -> fp8 table + L0 alpha dots ----------------
__global__ __launch_bounds__(256) void castx_alpha0(const float* __restrict__ x,
                                                    const float* __restrict__ va0,
                                                    u8* __restrict__ xq, float* __restrict__ asn,
                                                    float* __restrict__ adn) {
    int wid = threadIdx.x >> 6, lane = threadIdx.x & 63;
    int i = blockIdx.x * 4 + wid;
    if (i >= NN) return;
    f32x2 xv = *(const f32x2*)(x + (size_t)i * 128 + lane * 2);
    u32 q = __builtin_amdgcn_cvt_pk_fp8_f32(xv[0], xv[1], 0, false);
    *((u16*)(xq + (size_t)i * 128) + lane) = (u16)(q & 0xffff);
    float p[8];
#pragma unroll
    for (int j = 0; j < 8; j++) {
        f32x2 v = *(const f32x2*)(va0 + j * 128 + lane * 2);
        p[j] = xv[0] * v[0] + xv[1] * v[1];
    }
#pragma unroll
    for (int off = 32; off; off >>= 1)
#pragma unroll
        for (int j = 0; j < 8; j++) p[j] += __shfl_xor(p[j], off);
    if (lane == 0) {
        f32x4 o0 = {p[0], p[1], p[2], p[3]}, o1 = {p[4], p[5], p[6], p[7]};
        *(f32x4*)(asn + (size_t)i * 4) = o0;
        *(f32x4*)(adn + (size_t)i * 4) = o1;
    }
}

// ---------------- f16 MFMA GEMM; TK compile-time K ----------
template <int TK, bool BD, bool EPI, int OT>
__global__ __launch_bounds__(256) void gemm_t(const _Float16* __restrict__ A, int lda,
                                              const _Float16* __restrict__ Bt,
                                              void* __restrict__ Cv, int ldc, int M, int Nc,
                                              const float* __restrict__ sc,
                                              const float* __restrict__ sh) {
    __shared__ __align__(16) _Float16 As[2][128 * 64];
    __shared__ __align__(16) _Float16 Bs[2][128 * 64];
    const int t = threadIdx.x;
    const int bm = blockIdx.x * 128;
    const int bn = blockIdx.y * 128;
    const int wid = t >> 6, lane = t & 63;
    const int wm = (wid >> 1) * 64, wn = (wid & 1) * 64;
    const int aoff = BD ? bn : 0;
    f32x4 acc[4][4] = {};
    constexpr int nsteps = TK >> 6;

    auto STAGE = [&](int buf, int k0) {
#pragma unroll
        for (int it = 0; it < 4; ++it) {
            int rbase = it * 32 + wid * 8;
            int row = rbase + (lane >> 3);
            int c8g = (lane & 7) ^ (row & 7);
            gld_lds16(A + (size_t)(bm + row) * lda + aoff + k0 + c8g * 8,
                      (char*)As[buf] + rbase * 128);
            gld_lds16(Bt + (size_t)(bn + row) * TK + k0 + c8g * 8, (char*)Bs[buf] + rbase * 128);
        }
    };

    STAGE(0, 0);
    __syncthreads();
#pragma unroll
    for (int s = 0; s < nsteps; ++s) {
        const int cur = s & 1;
        if (s + 1 < nsteps) STAGE(cur ^ 1, (s + 1) * 64);
#pragma unroll
        for (int ks = 0; ks < 2; ++ks) {
            f16x8 af[4], bf[4];
#pragma unroll
            for (int mi = 0; mi < 4; ++mi) {
                int row = wm + mi * 16 + (lane & 15);
                int c8 = (ks * 4 + (lane >> 4)) ^ (row & 7);
                af[mi] = *(const f16x8*)((const char*)As[cur] + row * 128 + c8 * 16);
            }
#pragma unroll
            for (int ni = 0; ni < 4; ++ni) {
                int row = wn + ni * 16 + (lane & 15);
                int c8 = (ks * 4 + (lane >> 4)) ^ (row & 7);
                bf[ni] = *(const f16x8*)((const char*)Bs[cur] + row * 128 + c8 * 16);
            }
#pragma unroll
            for (int mi = 0; mi < 4; ++mi)
#pragma unroll
                for (int ni = 0; ni < 4; ++ni)
                    acc[mi][ni] = __builtin_amdgcn_mfma_f32_16x16x32_f16(af[mi], bf[ni],
                                                                         acc[mi][ni], 0, 0, 0);
        }
        __syncthreads();
    }
    float scv[4], shv[4];
    if (EPI) {
#pragma unroll
        for (int ni = 0; ni < 4; ++ni) {
            int gcol = bn + wn + ni * 16 + (lane & 15);
            scv[ni] = sc[gcol];
            shv[ni] = sh[gcol];
        }
    }
#pragma unroll
    for (int mi = 0; mi < 4; ++mi) {
#pragma unroll
        for (int r = 0; r < 4; ++r) {
            int grow = bm + wm + mi * 16 + (lane >> 4) * 4 + r;
            if (grow < M) {
#pragma unroll
                for (int ni = 0; ni < 4; ++ni) {
                    int gcol = bn + wn + ni * 16 + (lane & 15);
                    if (gcol < Nc) {
                        float v = acc[mi][ni][r];
                        if (EPI) {
                            v = v * scv[ni] + shv[ni];
                            v = v > 0.f ? v : expm1f(v);
                        }
                        if constexpr (OT == 0) {
                            ((_Float16*)Cv)[(size_t)grow * ldc + gcol] = (_Float16)v;
                        } else {
                            ((u8*)Cv)[(size_t)grow * ldc + gcol] = f32_to_fp8(v);
                        }
                    }
                }
            }
        }
    }
}

// ---------------- alpha L1/L2 ----------------
template <int JH, int STR>
__global__ __launch_bounds__(256) void alpha12(const _Float16* __restrict__ feat,
                                               const float* __restrict__ va,
                                               float* __restrict__ asn, float* __restrict__ adn) {
    int wid = threadIdx.x >> 6, lane = threadIdx.x & 63;
    int i = blockIdx.x * 4 + wid;
    if (i >= NN) return;
    f16x8 x8 = *(const f16x8*)(feat + (size_t)i * 512 + lane * 8);
    float xf[8];
#pragma unroll
    for (int u = 0; u < 8; u++) xf[u] = (float)x8[u];
    float p[2 * JH];
#pragma unroll
    for (int j = 0; j < 2 * JH; j++) {
        const float* vr = va + j * 512 + lane * 8;
        f32x4 v0 = *(const f32x4*)vr;
        f32x4 v1 = *(const f32x4*)(vr + 4);
        p[j] = xf[0] * v0[0] + xf[1] * v0[1] + xf[2] * v0[2] + xf[3] * v0[3] +
               xf[4] * v1[0] + xf[5] * v1[1] + xf[6] * v1[2] + xf[7] * v1[3];
    }
#pragma unroll
    for (int off = 32; off; off >>= 1)
#pragma unroll
        for (int j = 0; j < 2 * JH; j++) p[j] += __shfl_xor(p[j], off);
    if (lane == 0) {
#pragma unroll
        for (int h = 0; h < JH; h++) {
            asn[(size_t)i * STR + h] = p[h];
            adn[(size_t)i * STR + h] = p[JH + h];
        }
    }
}

// ---------------- L0: fused softmax + x-space aggregation (fp8 x, 4-edge unroll) ----------
__global__ __launch_bounds__(256) void aggx(const u8* __restrict__ xq,
                                            const float* __restrict__ asn,
                                            const float* __restrict__ adn,
                                            const int* __restrict__ rowptr,
                                            const int* __restrict__ csr,
                                            _Float16* __restrict__ xa) {
    __shared__ __align__(8) _Float16 wsl[4][64][4];
    int wid = threadIdx.x >> 6, lane = threadIdx.x & 63;
    int i = blockIdx.x * 4 + wid;
    if (i >= NN) return;
    int start = rfl(rowptr[i]), end = rfl(rowptr[i + 1]);
    int deg = end - start;
    bool fastp = deg <= 64;
    f32x4 ad = *(const f32x4*)(adn + (size_t)i * 4);
    f32x4 m4, rd4;
    if (fastp) {
        bool v = lane < deg;
        int e = start + (v ? lane : 0);
        int s = csr[e];
        f32x4 a = *(const f32x4*)(asn + (size_t)s * 4);
        f32x4 sc4, mm, wv, dn;
#pragma unroll
        for (int j = 0; j < 4; j++) { sc4[j] = v ? lrelu(a[j] + ad[j]) : -1e30f; mm[j] = sc4[j]; }
#pragma unroll
        for (int off = 32; off; off >>= 1)
#pragma unroll
            for (int j = 0; j < 4; j++) mm[j] = fmaxf(mm[j], __shfl_xor(mm[j], off));
#pragma unroll
        for (int j = 0; j < 4; j++) { wv[j] = v ? __expf(sc4[j] - mm[j]) : 0.f; dn[j] = wv[j]; }
#pragma unroll
        for (int off = 32; off; off >>= 1)
#pragma unroll
            for (int j = 0; j < 4; j++) dn[j] += __shfl_xor(dn[j], off);
        f16x4 o;
#pragma unroll
        for (int j = 0; j < 4; j++) o[j] = (_Float16)(wv[j] / (dn[j] + 1e-16f));
        *(f16x4*)&wsl[wid][lane][0] = o;
    } else {
        f32x4 mm = {-1e30f, -1e30f, -1e30f, -1e30f};
        for (int e = start + lane; e < end; e += 64) {
            int s = csr[e];
            f32x4 a = *(const f32x4*)(asn + (size_t)s * 4);
#pragma unroll
            for (int j = 0; j < 4; j++) mm[j] = fmaxf(mm[j], lrelu(a[j] + ad[j]));
        }
#pragma unroll
        for (int off = 32; off; off >>= 1)
#pragma unroll
            for (int j = 0; j < 4; j++) mm[j] = fmaxf(mm[j], __shfl_xor(mm[j], off));
        f32x4 dn = {0.f, 0.f, 0.f, 0.f};
        for (int e = start + lane; e < end; e += 64) {
            int s = csr[e];
            f32x4 a = *(const f32x4*)(asn + (size_t)s * 4);
#pragma unroll
            for (int j = 0; j < 4; j++) dn[j] += __expf(lrelu(a[j] + ad[j]) - mm[j]);
        }
#pragma unroll
        for (int off = 32; off; off >>= 1)
#pragma unroll
            for (int j = 0; j < 4; j++) dn[j] += __shfl_xor(dn[j], off);
        m4 = mm;
#pragma unroll
        for (int j = 0; j < 4; j++) rd4[j] = 1.f / (dn[j] + 1e-16f);
    }
    const char* xb = (const char*)xq + lane * 2;
    float acc[8] = {};
    int e = start;
    auto getw = [&](int ee, int ss, float* w) {
        if (fastp) {
            f16x4 wv4 = *(const f16x4*)&wsl[wid][ee - start][0];
#pragma unroll
            for (int h = 0; h < 4; h++) w[h] = (float)wv4[h];
        } else {
#pragma unroll
            for (int h = 0; h < 4; h++)
                w[h] = __expf(lrelu(asn[(size_t)ss * 4 + h] + ad[h]) - m4[h]) * rd4[h];
        }
    };
    for (; e + 4 <= end; e += 4) {
        int4 sv = *(const int4*)(csr + e);
        int s0 = rfl(sv.x), s1 = rfl(sv.y), s2 = rfl(sv.z), s3 = rfl(sv.w);
        u16 pv0 = *(const u16*)(xb + (u32)s0 * 128u);
        u16 pv1 = *(const u16*)(xb + (u32)s1 * 128u);
        u16 pv2 = *(const u16*)(xb + (u32)s2 * 128u);
        u16 pv3 = *(const u16*)(xb + (u32)s3 * 128u);
        float w0[4], w1[4], w2[4], w3[4];
        getw(e, s0, w0); getw(e + 1, s1, w1); getw(e + 2, s2, w2); getw(e + 3, s3, w3);
        f32x2 q0 = __builtin_amdgcn_cvt_pk_f32_fp8((u32)pv0, false);
        f32x2 q1 = __builtin_amdgcn_cvt_pk_f32_fp8((u32)pv1, false);
        f32x2 q2 = __builtin_amdgcn_cvt_pk_f32_fp8((u32)pv2, false);
        f32x2 q3 = __builtin_amdgcn_cvt_pk_f32_fp8((u32)pv3, false);
#pragma unroll
        for (int h = 0; h < 4; h++) {
            acc[h * 2]     += w0[h] * q0[0] + w1[h] * q1[0] + w2[h] * q2[0] + w3[h] * q3[0];
            acc[h * 2 + 1] += w0[h] * q0[1] + w1[h] * q1[1] + w2[h] * q2[1] + w3[h] * q3[1];
        }
    }
    for (; e < end; e++) {
        int s = rfl(csr[e]);
        float w[4];
        getw(e, s, w);
        u16 pv = *(const u16*)(xb + (u32)s * 128u);
        f32x2 q = __builtin_amdgcn_cvt_pk_f32_fp8((u32)pv, false);
#pragma unroll
        for (int h = 0; h < 4; h++) {
            acc[h * 2] += w[h] * q[0];
            acc[h * 2 + 1] += w[h] * q[1];
        }
    }
#pragma unroll
    for (int h = 0; h < 4; h++) {
        f16x2 o;
        o[0] = (_Float16)acc[h * 2];
        o[1] = (_Float16)acc[h * 2 + 1];
        *(f16x2*)(xa + (size_t)i * 512 + h * 128 + lane * 2) = o;
    }
}

// ---------------- L1: fused softmax + fp8 gather (2-edge; scalar indices) ----------
__global__ __launch_bounds__(256) void agg01(const u8* __restrict__ h,
                                             const float* __restrict__ asn,
                                             const float* __restrict__ adn,
                                             const int* __restrict__ rowptr,
                                             const int* __restrict__ csr,
                                             const float* __restrict__ sc,
                                             const float* __restrict__ sh,
                                             _Float16* __restrict__ out) {
    __shared__ __align__(8) _Float16 wsl[4][64][4];
    int wid = threadIdx.x >> 6, lane = threadIdx.x & 63;
    int i = blockIdx.x * 4 + wid;
    if (i >= NN) return;
    int start = rfl(rowptr[i]), end = rfl(rowptr[i + 1]);
    int deg = end - start;
    bool fastp = deg <= 64;
    f32x4 ad = *(const f32x4*)(adn + (size_t)i * 4);
    f32x4 m4, rd4;
    if (fastp) {
        bool v = lane < deg;
        int e = start + (v ? lane : 0);
        int s = csr[e];
        f32x4 a = *(const f32x4*)(asn + (size_t)s * 4);
        f32x4 sc4, mm, wv, dn;
#pragma unroll
        for (int j = 0; j < 4; j++) { sc4[j] = v ? lrelu(a[j] + ad[j]) : -1e30f; mm[j] = sc4[j]; }
#pragma unroll
        for (int off = 32; off; off >>= 1)
#pragma unroll
            for (int j = 0; j < 4; j++) mm[j] = fmaxf(mm[j], __shfl_xor(mm[j], off));
#pragma unroll
        for (int j = 0; j < 4; j++) { wv[j] = v ? __expf(sc4[j] - mm[j]) : 0.f; dn[j] = wv[j]; }
#pragma unroll
        for (int off = 32; off; off >>= 1)
#pragma unroll
            for (int j = 0; j < 4; j++) dn[j] += __shfl_xor(dn[j], off);
        f16x4 o;
#pragma unroll
        for (int j = 0; j < 4; j++) o[j] = (_Float16)(wv[j] / (dn[j] + 1e-16f));
        *(f16x4*)&wsl[wid][lane][0] = o;
    } else {
        f32x4 mm = {-1e30f, -1e30f, -1e30f, -1e30f};
        for (int e = start + lane; e < end; e += 64) {
            int s = csr[e];
            f32x4 a = *(const f32x4*)(asn + (size_t)s * 4);
#pragma unroll
            for (int j = 0; j < 4; j++) mm[j] = fmaxf(mm[j], lrelu(a[j] + ad[j]));
        }
#pragma unroll
        for (int off = 32; off; off >>= 1)
#pragma unroll
            for (int j = 0; j < 4; j++) mm[j] = fmaxf(mm[j], __shfl_xor(mm[j], off));
        f32x4 dn = {0.f, 0.f, 0.f, 0.f};
        for (int e = start + lane; e < end; e += 64) {
            int s = csr[e];
            f32x4 a = *(const f32x4*)(asn + (size_t)s * 4);
#pragma unroll
            for (int j = 0; j < 4; j++) dn[j] += __expf(lrelu(a[j] + ad[j]) - mm[j]);
        }
#pragma unroll
        for (int off = 32; off; off >>= 1)
#pragma unroll
            for (int j = 0; j < 4; j++) dn[j] += __shfl_xor(dn[j], off);
        m4 = mm;
#pragma unroll
        for (int j = 0; j < 4; j++) rd4[j] = 1.f / (dn[j] + 1e-16f);
    }
    int head = lane >> 4;
    const char* hb = (const char*)h + lane * 8;
    float acc0[8] = {}, acc1[8] = {};
    int e = start;
    for (; e + 2 <= end; e += 2) {
        int2 sv = *(const int2*)(csr + e);
        int s0 = rfl(sv.x), s1 = rfl(sv.y);
        float w0, w1;
        if (fastp) {
            w0 = (float)wsl[wid][e - start][head];
            w1 = (float)wsl[wid][e + 1 - start][head];
        } else {
            w0 = __expf(lrelu(asn[(size_t)s0 * 4 + head] + ad[head]) - m4[head]) * rd4[head];
            w1 = __expf(lrelu(asn[(size_t)s1 * 4 + head] + ad[head]) - m4[head]) * rd4[head];
        }
        uint2 p0 = *(const uint2*)(hb + (u32)s0 * 512u);
        uint2 p1 = *(const uint2*)(hb + (u32)s1 * 512u);
        float q0[8], q1[8];
        fp8x4_to_f32(p0.x, q0); fp8x4_to_f32(p0.y, q0 + 4);
        fp8x4_to_f32(p1.x, q1); fp8x4_to_f32(p1.y, q1 + 4);
#pragma unroll
        for (int j = 0; j < 8; j++) {
            acc0[j] += w0 * q0[j];
            acc1[j] += w1 * q1[j];
        }
    }
    if (e < end) {
        int s0 = rfl(csr[e]);
        float w0;
        if (fastp) w0 = (float)wsl[wid][e - start][head];
        else w0 = __expf(lrelu(asn[(size_t)s0 * 4 + head] + ad[head]) - m4[head]) * rd4[head];
        uint2 p0 = *(const uint2*)(hb + (u32)s0 * 512u);
        float q0[8];
        fp8x4_to_f32(p0.x, q0); fp8x4_to_f32(p0.y, q0 + 4);
#pragma unroll
        for (int j = 0; j < 8; j++) acc0[j] += w0 * q0[j];
    }
    int ch = lane * 8;
    f32x4 sc0 = *(const f32x4*)(sc + ch), sc1 = *(const f32x4*)(sc + ch + 4);
    f32x4 sh0 = *(const f32x4*)(sh + ch), sh1 = *(const f32x4*)(sh + ch + 4);
    f16x8 o;
#pragma unroll
    for (int j = 0; j < 8; j++) {
        float s = (j < 4) ? sc0[j] : sc1[j - 4];
        float b = (j < 4) ? sh0[j] : sh1[j - 4];
        float val = (acc0[j] + acc1[j]) * s + b;
        val = val > 0.f ? val : expm1f(val);
        o[j] = (_Float16)val;
    }
    *(f16x8*)(out + (size_t)i * 512 + ch) = o;
}

// ---------------- L2: fused softmax (6 heads) + fp8 gather (4-edge) + log_softmax ----------
__global__ __launch_bounds__(256) void agg2f(const u8* __restrict__ h2,
                                             const float* __restrict__ asn,
                                             const float* __restrict__ adn,
                                             const int* __restrict__ rowptr,
                                             const int* __restrict__ csr,
                                             const float* __restrict__ b2,
                                             float* __restrict__ out) {
    __shared__ __align__(16) _Float16 wsl[4][64][8];
    __shared__ float sval[4][240];
    int wid = threadIdx.x >> 6, lane = threadIdx.x & 63;
    int i = blockIdx.x * 4 + wid;
    if (i < NN) {
        int start = rfl(rowptr[i]), end = rfl(rowptr[i + 1]);
        int deg = end - start;
        bool fastp = deg <= 64;
        f32x4 ad0 = *(const f32x4*)(adn + (size_t)i * 8);
        f32x4 ad1 = *(const f32x4*)(adn + (size_t)i * 8 + 4);
        float adh[6] = {ad0[0], ad0[1], ad0[2], ad0[3], ad1[0], ad1[1]};
        float m6[6], rd6[6];
        if (fastp) {
            bool v = lane < deg;
            int e = start + (v ? lane : 0);
            int s = csr[e];
            f32x4 x0 = *(const f32x4*)(asn + (size_t)s * 8);
            f32x4 x1 = *(const f32x4*)(asn + (size_t)s * 8 + 4);
            float av[6] = {x0[0], x0[1], x0[2], x0[3], x1[0], x1[1]};
            float sc6[6], mm[6], wv[6], dn[6];
#pragma unroll
            for (int j = 0; j < 6; j++) {
                sc6[j] = v ? lrelu(av[j] + adh[j]) : -1e30f;
                mm[j] = sc6[j];
            }
#pragma unroll
            for (int off = 32; off; off >>= 1)
#pragma unroll
                for (int j = 0; j < 6; j++) mm[j] = fmaxf(mm[j], __shfl_xor(mm[j], off));
#pragma unroll
            for (int j = 0; j < 6; j++) { wv[j] = v ? __expf(sc6[j] - mm[j]) : 0.f; dn[j] = wv[j]; }
#pragma unroll
            for (int off = 32; off; off >>= 1)
#pragma unroll
                for (int j = 0; j < 6; j++) dn[j] += __shfl_xor(dn[j], off);
            f16x8 o;
#pragma unroll
            for (int j = 0; j < 6; j++) o[j] = (_Float16)(wv[j] / (dn[j] + 1e-16f));
            o[6] = (_Float16)0.f;
            o[7] = (_Float16)0.f;
            *(f16x8*)&wsl[wid][lane][0] = o;
        } else {
            float mm[6], dn[6];
#pragma unroll
            for (int j = 0; j < 6; j++) { mm[j] = -1e30f; dn[j] = 0.f; }
            for (int e = start + lane; e < end; e += 64) {
                int s = csr[e];
                f32x4 x0 = *(const f32x4*)(asn + (size_t)s * 8);
                f32x4 x1 = *(const f32x4*)(asn + (size_t)s * 8 + 4);
                float av[6] = {x0[0], x0[1], x0[2], x0[3], x1[0], x1[1]};
#pragma unroll
                for (int j = 0; j < 6; j++) mm[j] = fmaxf(mm[j], lrelu(av[j] + adh[j]));
            }
#pragma unroll
            for (int off = 32; off; off >>= 1)
#pragma unroll
                for (int j = 0; j < 6; j++) mm[j] = fmaxf(mm[j], __shfl_xor(mm[j], off));
            for (int e = start + lane; e < end; e += 64) {
                int s = csr[e];
                f32x4 x0 = *(const f32x4*)(asn + (size_t)s * 8);
                f32x4 x1 = *(const f32x4*)(asn + (size_t)s * 8 + 4);
                float av[6] = {x0[0], x0[1], x0[2], x0[3], x1[0], x1[1]};
#pragma unroll
                for (int j = 0; j < 6; j++) dn[j] += __expf(lrelu(av[j] + adh[j]) - mm[j]);
            }
#pragma unroll
            for (int off = 32; off; off >>= 1)
#pragma unroll
                for (int j = 0; j < 6; j++) dn[j] += __shfl_xor(dn[j], off);
#pragma unroll
            for (int j = 0; j < 6; j++) { m6[j] = mm[j]; rd6[j] = 1.f / (dn[j] + 1e-16f); }
        }
        int head = (lane < 60) ? (lane / 10) : 0;
        const char* hb = (const char*)h2 + lane * 4;
        float a0[4] = {}, a1[4] = {};
        int e = start;
        auto getw1 = [&](int ee, int ss) -> float {
            if (fastp) return (float)wsl[wid][ee - start][head];
            return __expf(lrelu(asn[(size_t)ss * 8 + head] + adh[head]) - m6[head]) * rd6[head];
        };
        for (; e + 4 <= end; e += 4) {
            int4 sv = *(const int4*)(csr + e);
            int s0 = rfl(sv.x), s1 = rfl(sv.y), s2 = rfl(sv.z), s3 = rfl(sv.w);
            u32 p0 = *(const u32*)(hb + (u32)s0 * 256u);
            u32 p1 = *(const u32*)(hb + (u32)s1 * 256u);
            u32 p2 = *(const u32*)(hb + (u32)s2 * 256u);
            u32 p3 = *(const u32*)(hb + (u32)s3 * 256u);
            float w0 = getw1(e, s0), w1 = getw1(e + 1, s1);
            float w2 = getw1(e + 2, s2), w3 = getw1(e + 3, s3);
            float q0[4], q1[4], q2[4], q3[4];
            fp8x4_to_f32(p0, q0);
            fp8x4_to_f32(p1, q1);
            fp8x4_to_f32(p2, q2);
            fp8x4_to_f32(p3, q3);
#pragma unroll
            for (int j = 0; j < 4; j++) {
                a0[j] += w0 * q0[j] + w2 * q2[j];
                a1[j] += w1 * q1[j] + w3 * q3[j];
            }
        }
        for (; e < end; e++) {
            int s0 = rfl(csr[e]);
            float w0 = getw1(e, s0);
            u32 p0 = *(const u32*)(hb + (u32)s0 * 256u);
            float q0[4];
            fp8x4_to_f32(p0, q0);
#pragma unroll
            for (int j = 0; j < 4; j++) a0[j] += w0 * q0[j];
        }
        if (lane < 60) {
#pragma unroll
            for (int j = 0; j < 4; j++) sval[wid][lane * 4 + j] = a0[j] + a1[j];
        }
    }
    __syncthreads();
    if (i < NN) {
        float v = -INFINITY;
        if (lane < 40) {
            float s = 0.f;
#pragma unroll
            for (int hh = 0; hh < 6; hh++) s += sval[wid][hh * 40 + lane];
            v = s * (1.0f / 6.0f) + b2[lane];
        }
        float mm = v;
#pragma unroll
        for (int off = 32; off; off >>= 1) mm = fmaxf(mm, __shfl_xor(mm, off));
        float se = (lane < 40) ? __expf(v - mm) : 0.f;
#pragma unroll
        for (int off = 32; off; off >>= 1) se += __shfl_xor(se, off);
        if (lane < 40) out[(size_t)i * 40 + lane] = v - mm - logf(se);
    }
}

extern "C" void kernel_launch(void* const* d_in, const int* in_sizes, int n_in,
                              void* d_out, int out_size, void* d_ws, size_t ws_size,
                              hipStream_t stream) {
    const float* x   = (const float*)d_in[0];
    const int*   ei  = (const int*)d_in[1];
    const float* W0  = (const float*)d_in[2];
    const float* as0 = (const float*)d_in[3];
    const float* ad0 = (const float*)d_in[4];
    const float* b0  = (const float*)d_in[5];
    const float* g0  = (const float*)d_in[6];
    const float* bt0 = (const float*)d_in[7];
    const float* m0  = (const float*)d_in[8];
    const float* v0  = (const float*)d_in[9];
    const float* W1  = (const float*)d_in[10];
    const float* as1 = (const float*)d_in[11];
    const float* ad1 = (const float*)d_in[12];
    const float* b1  = (const float*)d_in[13];
    const float* g1  = (const float*)d_in[14];
    const float* bt1 = (const float*)d_in[15];
    const float* m1  = (const float*)d_in[16];
    const float* v1  = (const float*)d_in[17];
    const float* W2  = (const float*)d_in[18];
    const float* as2w = (const float*)d_in[19];
    const float* ad2w = (const float*)d_in[20];
    const float* b2  = (const float*)d_in[21];
    float* out = (float*)d_out;
    const int* srcv = ei;
    const int* dstv = ei + EE;

    char* w = (char*)d_ws;
    auto carve = [&](size_t bytes) {
        char* p = w;
        w += (bytes + 255) & ~(size_t)255;
        return p;
    };
    u32* xq        = (u32*)carve((size_t)NN * 128);
    _Float16* hA   = (_Float16*)carve((size_t)NN * 512 * 2);
    _Float16* actB = (_Float16*)carve((size_t)NN * 512 * 2);
    _Float16* W0t  = (_Float16*)carve((size_t)512 * 128 * 2);
    _Float16* W1t  = (_Float16*)carve((size_t)512 * 512 * 2);
    _Float16* W2t  = (_Float16*)carve((size_t)240 * 512 * 2);
    float* va0  = (float*)carve((size_t)8 * 128 * 4);
    float* va1  = (float*)carve((size_t)8 * 512 * 4);
    float* va2  = (float*)carve((size_t)12 * 512 * 4);
    float* sc01 = (float*)carve((size_t)1024 * 4);
    float* sh01 = (float*)carve((size_t)1024 * 4);
    float* asn  = (float*)carve((size_t)NN * 8 * 4);
    float* adn  = (float*)carve((size_t)NN * 8 * 4);
    int* count  = (int*)carve((size_t)(NN + 8) * 4);
    int* excl   = (int*)carve((size_t)(NN + 8) * 4);
    int* bsum   = (int*)carve((size_t)512 * 4);
    int* rowptr = (int*)carve((size_t)(NN + 8) * 4);
    int* cursor = (int*)carve((size_t)(NN + 8) * 4);
    int* csrs   = (int*)carve((size_t)(EPQ + 8) * 4);
    _Float16* xa = hA;
    u8* h1q  = (u8*)hA;
    u8* h2q  = (u8*)hA;

    // CSR build
    hipMemsetAsync(count, 0, (size_t)NN * 4, stream);
    hist_kernel<<<(EE + 255) / 256, 256, 0, stream>>>(dstv, count);
    scan1<<<NBLK, SCB, 0, stream>>>(count, excl, bsum);
    scan23<<<(NN + 256) / 256, 256, 0, stream>>>(excl, bsum, rowptr, cursor);
    scatter_kernel<<<(EPQ + 255) / 256, 256, 0, stream>>>(srcv, dstv, cursor, csrs);

    // weights + prep (merged)
    tcast_all<<<448, 256, 0, stream>>>(W0, W1, W2, W0t, W1t, W2t);
    prep_all<<<29, 1024, 0, stream>>>(g0, bt0, m0, v0, b0, g1, bt1, m1, v1, b1, W0t, W1t, W2t,
                                      as0, ad0, as1, ad1, as2w, ad2w, sc01, sh01, va0, va1, va2);

    const int MT = (NN + 127) / 128;   // 391
    const int NG = (NN + 3) / 4;       // 12500

    // Layer 0
    castx_alpha0<<<NG, 256, 0, stream>>>(x, va0, (u8*)xq, asn, adn);
    aggx<<<NG, 256, 0, stream>>>((const u8*)xq, asn, adn, rowptr, csrs, xa);
    gemm_t<128, true, true, 0><<<dim3(MT, 4), 256, 0, stream>>>(xa, 512, W0t, actB, 512, NN, 512,
                                                                sc01, sh01);

    // Layer 1
    gemm_t<512, false, false, 1><<<dim3(MT, 4), 256, 0, stream>>>(actB, 512, W1t, h1q, 512, NN,
                                                                  512, nullptr, nullptr);
    alpha12<4, 4><<<NG, 256, 0, stream>>>(actB, va1, asn, adn);
    agg01<<<NG, 256, 0, stream>>>(h1q, asn, adn, rowptr, csrs, sc01 + 512, sh01 + 512, actB);

    // Layer 2
    gemm_t<512, false, false, 1><<<dim3(MT, 2), 256, 0, stream>>>(actB, 512, W2t, h2q, 256, NN,
                                                                  240, nullptr, nullptr);
    alpha12<6, 8><<<NG, 256, 0, stream>>>(actB, va2, asn, adn);
    agg2f<<<NG, 256, 0, stream>>>(h2q, asn, adn, rowptr, csrs, b2, out);
}